// Round 8
// baseline (539.904 us; speedup 1.0000x reference)
//
#include <hip/hip_runtime.h>

#define NDIM 128
#define EDIM 64
#define BN_EPS 1e-5f
#define WPB  4           // waves per block (edge pass)
#define MPITCH 136       // edge-pass msg row pitch in shorts (272B)
#define PITCH 136        // node-mlp LDS row pitch in shorts

typedef __attribute__((ext_vector_type(8))) short short8v;
typedef __attribute__((ext_vector_type(4))) float float4v;

static __device__ __forceinline__ unsigned short f2bf(float f) {
    union { float f; unsigned u; } c; c.f = f;
    const unsigned r = (c.u + 0x7fffu + ((c.u >> 16) & 1u)) >> 16;
    return (unsigned short)r;
}
static __device__ __forceinline__ float bf2f(unsigned short u) {
    union { unsigned u; float f; } c; c.u = ((unsigned)u) << 16;
    return c.f;
}

static __device__ __forceinline__ short8v cvt_row(const float* __restrict__ arow, int k0) {
    const float4 f0 = *reinterpret_cast<const float4*>(arow + k0);
    const float4 f1 = *reinterpret_cast<const float4*>(arow + k0 + 4);
    short8v a;
    a[0] = (short)f2bf(f0.x); a[1] = (short)f2bf(f0.y);
    a[2] = (short)f2bf(f0.z); a[3] = (short)f2bf(f0.w);
    a[4] = (short)f2bf(f1.x); a[5] = (short)f2bf(f1.y);
    a[6] = (short)f2bf(f1.z); a[7] = (short)f2bf(f1.w);
    return a;
}

// ---------------------------------------------------------------------------
// CSR build step 1: degree histogram over dst.
// ---------------------------------------------------------------------------
__global__ __launch_bounds__(256) void hist_k(
    const int* __restrict__ ei, int* __restrict__ deg, int E)
{
    const int e = blockIdx.x * blockDim.x + threadIdx.x;
    if (e < E) atomicAdd(&deg[ei[E + e]], 1);
}

// ---------------------------------------------------------------------------
// CSR build step 2: exclusive scan of deg -> rowptr + cursor.
// ---------------------------------------------------------------------------
__global__ __launch_bounds__(1024) void scan_build(
    int* __restrict__ cursor, int* __restrict__ rowptr, int N)
{
    __shared__ int wsums[16];
    __shared__ int run_s;
    const int tid  = threadIdx.x;
    const int lane = tid & 63;
    const int w    = tid >> 6;
    if (tid == 0) run_s = 0;
    __syncthreads();
    for (int base = 0; base < N; base += 1024) {
        const int i = base + tid;
        const int v = (i < N) ? cursor[i] : 0;
        int incl = v;
#pragma unroll
        for (int off = 1; off < 64; off <<= 1) {
            int t = __shfl_up(incl, off, 64);
            if (lane >= off) incl += t;
        }
        if (lane == 63) wsums[w] = incl;
        __syncthreads();
        if (w == 0) {
            int s = (lane < 16) ? wsums[lane] : 0;
#pragma unroll
            for (int off = 1; off < 16; off <<= 1) {
                int t = __shfl_up(s, off, 64);
                if (lane >= off) s += t;
            }
            if (lane < 16) wsums[lane] = s;
        }
        __syncthreads();
        const int waveoff = (w > 0) ? wsums[w - 1] : 0;
        const int run = run_s;
        const int excl = run + waveoff + incl - v;
        if (i < N) { rowptr[i] = excl; cursor[i] = excl; }
        __syncthreads();
        if (tid == 0) run_s += wsums[15];
        __syncthreads();
    }
    if (tid == 0) rowptr[N] = run_s;
}

// ---------------------------------------------------------------------------
// CSR build step 3: scatter src / edge-id / dst into slot order.
// ---------------------------------------------------------------------------
__global__ __launch_bounds__(256) void scatter_k(
    const int* __restrict__ ei, int* __restrict__ cursor,
    int* __restrict__ srcp, int* __restrict__ eidp, int* __restrict__ dstp, int E)
{
    const int e = blockIdx.x * blockDim.x + threadIdx.x;
    if (e < E) {
        const int d = ei[E + e];
        const int p = atomicAdd(&cursor[d], 1);
        srcp[p] = ei[e];
        eidp[p] = e;
        dstp[p] = d;
    }
}

// ---------------------------------------------------------------------------
// Weight prep (merged): We1/We2 -> [128][64] bf16T; W1..W4 -> [128][128] bf16T.
// ---------------------------------------------------------------------------
__global__ __launch_bounds__(128) void prep_all(
    const float* __restrict__ We1, const float* __restrict__ We2,
    const float* __restrict__ W1, const float* __restrict__ W2,
    const float* __restrict__ W3, const float* __restrict__ W4,
    unsigned short* __restrict__ WeT1, unsigned short* __restrict__ WeT2,
    unsigned short* __restrict__ W1T, unsigned short* __restrict__ W2T,
    unsigned short* __restrict__ W3T, unsigned short* __restrict__ W4T)
{
    const int c = blockIdx.x;    // 0..127 output column
    const int k = threadIdx.x;   // 0..127
    if (k < EDIM) {
        WeT1[c * EDIM + k] = f2bf(We1[k * NDIM + c]);
        WeT2[c * EDIM + k] = f2bf(We2[k * NDIM + c]);
    }
    W1T[c * NDIM + k] = f2bf(W1[k * NDIM + c]);
    W2T[c * NDIM + k] = f2bf(W2[k * NDIM + c]);
    W3T[c * NDIM + k] = f2bf(W3[k * NDIM + c]);
    W4T[c * NDIM + k] = f2bf(W4[k * NDIM + c]);
}

// ---------------------------------------------------------------------------
// Edge pass, MFMA + software-pipelined segmented accumulate, persistent grid.
// Each wave owns a contiguous range of 16-slot tiles; pipeline runs across
// the whole range (one prologue per wave). msg staged in bf16 LDS.
// ---------------------------------------------------------------------------
__global__ __launch_bounds__(256, 3) void edge_mfma(
    const float* __restrict__ xnode,          // [N,128]
    const float* __restrict__ ea,             // [E,64] edge order
    const int*   __restrict__ srcp,           // [E] slot-ordered src
    const int*   __restrict__ eidp,           // [E] slot-ordered edge id
    const int*   __restrict__ dstp,           // [E] slot-ordered dst (sorted)
    const unsigned short* __restrict__ WeT,   // [128][64] bf16
    const float* __restrict__ be,             // [128]
    float*       __restrict__ aggr,           // [N,128] pre-zeroed
    int E)
{
    __shared__ unsigned short msg[WPB][16][MPITCH];

    const int tid  = threadIdx.x;
    const int lane = tid & 63;
    const int wv   = tid >> 6;

    const int m16 = lane & 15;   // A row (slot-within-tile) / C col-within-ntile
    const int kg  = lane >> 4;   // k-group 0..3
    const int k0a = kg * 8;

    // B fragments: full We resident (2 k-tiles x 8 n-tiles = 64 VGPR)
    short8v bfrag[2][8];
#pragma unroll
    for (int kk = 0; kk < 2; ++kk)
#pragma unroll
        for (int nt = 0; nt < 8; ++nt) {
            const int col = nt * 16 + m16;
            bfrag[kk][nt] = *reinterpret_cast<const short8v*>(&WeT[col * EDIM + kk * 32 + k0a]);
        }

    const int c0 = lane, c1 = lane + 64;
    const float be0 = be[c0], be1 = be[c1];
    unsigned short* msgw = &msg[wv][0][0];

    // ---- tile-range split ----
    const int T  = E >> 4;                       // full 16-slot tiles
    const int W  = blockIdx.x * WPB + wv;
    const int nw = gridDim.x * WPB;
    const int q  = T / nw, rr = T % nw;
    const int t0 = W * q + (W < rr ? W : rr);
    const int cnt = q + (W < rr ? 1 : 0);

    if (cnt > 0) {
        const int s0 = t0 << 4;
        int   sr_c[16], ds_c[16];
        float xv0_c[16], xv1_c[16];
        short8v af_c[2];

        // ---- prologue: tile 0 of range ----
#pragma unroll
        for (int s = 0; s < 16; ++s) { sr_c[s] = srcp[s0 + s]; ds_c[s] = dstp[s0 + s]; }
#pragma unroll
        for (int s = 0; s < 16; ++s) {
            xv0_c[s] = xnode[(long)sr_c[s] * NDIM + c0];
            xv1_c[s] = xnode[(long)sr_c[s] * NDIM + c1];
        }
        {
            const float* arow = ea + (long)eidp[s0 + m16] * EDIM;
            af_c[0] = cvt_row(arow, k0a);
            af_c[1] = cvt_row(arow, 32 + k0a);
        }
#pragma unroll
        for (int nt = 0; nt < 8; ++nt) {
            float4v acc = (float4v){0.f, 0.f, 0.f, 0.f};
            acc = __builtin_amdgcn_mfma_f32_16x16x32_bf16(af_c[0], bfrag[0][nt], acc, 0, 0, 0);
            acc = __builtin_amdgcn_mfma_f32_16x16x32_bf16(af_c[1], bfrag[1][nt], acc, 0, 0, 0);
#pragma unroll
            for (int r = 0; r < 4; ++r)
                msgw[(kg * 4 + r) * MPITCH + nt * 16 + m16] = f2bf(acc[r]);
        }

        float a0 = 0.f, a1 = 0.f;
        int dcur = ds_c[0];

        for (int t = 0; t < cnt; ++t) {
            const int base = s0 + (t << 4);
            int   sr_n[16], ds_n[16];
            float xv0_n[16], xv1_n[16];
            short8v af_n[2];
            const bool hn = (t + 1 < cnt);

            // ---- load phase for tile t+1 (issued before flush of t) ----
            if (hn) {
#pragma unroll
                for (int s = 0; s < 16; ++s) {
                    sr_n[s] = srcp[base + 16 + s];
                    ds_n[s] = dstp[base + 16 + s];
                }
#pragma unroll
                for (int s = 0; s < 16; ++s) {
                    xv0_n[s] = xnode[(long)sr_n[s] * NDIM + c0];
                    xv1_n[s] = xnode[(long)sr_n[s] * NDIM + c1];
                }
                const float* arow = ea + (long)eidp[base + 16 + m16] * EDIM;
                af_n[0] = cvt_row(arow, k0a);
                af_n[1] = cvt_row(arow, 32 + k0a);
            }

            // ---- flush tile t: registers + LDS msg reads, no global loads ----
#pragma unroll
            for (int s = 0; s < 16; ++s) {
                if (ds_c[s] != dcur) {
                    atomicAdd(&aggr[(long)dcur * NDIM + c0], a0);
                    atomicAdd(&aggr[(long)dcur * NDIM + c1], a1);
                    a0 = 0.f; a1 = 0.f; dcur = ds_c[s];
                }
                a0 += fmaxf(xv0_c[s] + bf2f(msgw[s * MPITCH + c0]) + be0, 0.f);
                a1 += fmaxf(xv1_c[s] + bf2f(msgw[s * MPITCH + c1]) + be1, 0.f);
            }

            // ---- MFMA + stage tile t+1 ----
            if (hn) {
#pragma unroll
                for (int nt = 0; nt < 8; ++nt) {
                    float4v acc = (float4v){0.f, 0.f, 0.f, 0.f};
                    acc = __builtin_amdgcn_mfma_f32_16x16x32_bf16(af_n[0], bfrag[0][nt], acc, 0, 0, 0);
                    acc = __builtin_amdgcn_mfma_f32_16x16x32_bf16(af_n[1], bfrag[1][nt], acc, 0, 0, 0);
#pragma unroll
                    for (int r = 0; r < 4; ++r)
                        msgw[(kg * 4 + r) * MPITCH + nt * 16 + m16] = f2bf(acc[r]);
                }
#pragma unroll
                for (int s = 0; s < 16; ++s) {
                    sr_c[s] = sr_n[s]; ds_c[s] = ds_n[s];
                    xv0_c[s] = xv0_n[s]; xv1_c[s] = xv1_n[s];
                }
            }
        }
        atomicAdd(&aggr[(long)dcur * NDIM + c0], a0);
        atomicAdd(&aggr[(long)dcur * NDIM + c1], a1);
    }

    // ---- tail edges [T*16, E) handled by the last wave (slow path) ----
    if ((E & 15) && W == nw - 1) {
        const int base = T << 4;
        const int slot = (base + m16 < E) ? base + m16 : E - 1;
        const float* arow = ea + (long)eidp[slot] * EDIM;
        short8v afrag[2];
        afrag[0] = cvt_row(arow, k0a);
        afrag[1] = cvt_row(arow, 32 + k0a);
#pragma unroll
        for (int nt = 0; nt < 8; ++nt) {
            float4v acc = (float4v){0.f, 0.f, 0.f, 0.f};
            acc = __builtin_amdgcn_mfma_f32_16x16x32_bf16(afrag[0], bfrag[0][nt], acc, 0, 0, 0);
            acc = __builtin_amdgcn_mfma_f32_16x16x32_bf16(afrag[1], bfrag[1][nt], acc, 0, 0, 0);
#pragma unroll
            for (int r = 0; r < 4; ++r)
                msgw[(kg * 4 + r) * MPITCH + nt * 16 + m16] = f2bf(acc[r]);
        }
        float a0 = 0.f, a1 = 0.f;
        int dcur = dstp[base];
        for (int s = 0; s < 16; ++s) {
            const int gs = base + s;
            if (gs >= E) break;
            const int d  = dstp[gs];
            const int sr = srcp[gs];
            if (d != dcur) {
                atomicAdd(&aggr[(long)dcur * NDIM + c0], a0);
                atomicAdd(&aggr[(long)dcur * NDIM + c1], a1);
                a0 = 0.f; a1 = 0.f; dcur = d;
            }
            a0 += fmaxf(xnode[(long)sr * NDIM + c0] + bf2f(msgw[s * MPITCH + c0]) + be0, 0.f);
            a1 += fmaxf(xnode[(long)sr * NDIM + c1] + bf2f(msgw[s * MPITCH + c1]) + be1, 0.f);
        }
        atomicAdd(&aggr[(long)dcur * NDIM + c0], a0);
        atomicAdd(&aggr[(long)dcur * NDIM + c1], a1);
    }
}

// ---------------------------------------------------------------------------
// Node MLP via MFMA (round-7, kept).
// ---------------------------------------------------------------------------
template <bool FINAL_RELU, bool STATS>
__global__ __launch_bounds__(256) void node_mlp_mfma(
    const float* xin,                    // may alias out (same-row read->write)
    const float* __restrict__ aggr,
    const unsigned short* __restrict__ W1T, const float* __restrict__ b1,
    const unsigned short* __restrict__ W2T, const float* __restrict__ b2,
    float* out,
    float* __restrict__ stats,
    int N)
{
    __shared__ unsigned short in_lds[16][PITCH];
    __shared__ unsigned short t_lds[16][PITCH];

    const int tid  = threadIdx.x;
    const int lane = tid & 63;
    const int wv   = tid >> 6;
    const int wn0  = wv * 32;
    const int m16  = lane & 15;
    const int rg   = lane >> 4;

    short8v b1f[4][2], b2f[4][2];
#pragma unroll
    for (int kt = 0; kt < 4; ++kt)
#pragma unroll
        for (int nt = 0; nt < 2; ++nt) {
            const int col = wn0 + nt * 16 + m16;
            b1f[kt][nt] = *reinterpret_cast<const short8v*>(&W1T[col * NDIM + kt * 32 + rg * 8]);
            b2f[kt][nt] = *reinterpret_cast<const short8v*>(&W2T[col * NDIM + kt * 32 + rg * 8]);
        }
    float bias1[2], bias2[2];
#pragma unroll
    for (int nt = 0; nt < 2; ++nt) {
        bias1[nt] = b1[wn0 + nt * 16 + m16];
        bias2[nt] = b2[wn0 + nt * 16 + m16];
    }

    float ss[2] = {0.f, 0.f}, sq[2] = {0.f, 0.f};

    const int ntile = (N + 15) >> 4;
    for (int tile = blockIdx.x; tile < ntile; tile += gridDim.x) {
        const int nb = tile << 4;

        {
            const int row = tid >> 4;
            const int ch  = tid & 15;
            const int gr  = nb + row;
            short8v pk = (short8v){0, 0, 0, 0, 0, 0, 0, 0};
            if (gr < N) {
                const float4* xp = reinterpret_cast<const float4*>(xin  + (size_t)gr * NDIM + ch * 8);
                const float4* ap = reinterpret_cast<const float4*>(aggr + (size_t)gr * NDIM + ch * 8);
                const float4 x0 = xp[0], x1 = xp[1];
                const float4 g0 = ap[0], g1 = ap[1];
                pk[0] = (short)f2bf(x0.x + g0.x); pk[1] = (short)f2bf(x0.y + g0.y);
                pk[2] = (short)f2bf(x0.z + g0.z); pk[3] = (short)f2bf(x0.w + g0.w);
                pk[4] = (short)f2bf(x1.x + g1.x); pk[5] = (short)f2bf(x1.y + g1.y);
                pk[6] = (short)f2bf(x1.z + g1.z); pk[7] = (short)f2bf(x1.w + g1.w);
            }
            *reinterpret_cast<short8v*>(&in_lds[row][ch * 8]) = pk;
        }
        __syncthreads();

        short8v af[4];
#pragma unroll
        for (int kt = 0; kt < 4; ++kt)
            af[kt] = *reinterpret_cast<const short8v*>(&in_lds[m16][kt * 32 + rg * 8]);
        float4v acc[2];
#pragma unroll
        for (int nt = 0; nt < 2; ++nt) {
            acc[nt] = (float4v){0.f, 0.f, 0.f, 0.f};
#pragma unroll
            for (int kt = 0; kt < 4; ++kt)
                acc[nt] = __builtin_amdgcn_mfma_f32_16x16x32_bf16(af[kt], b1f[kt][nt], acc[nt], 0, 0, 0);
        }
#pragma unroll
        for (int nt = 0; nt < 2; ++nt)
#pragma unroll
            for (int r = 0; r < 4; ++r) {
                const float v = fmaxf(acc[nt][r] + bias1[nt], 0.f);
                t_lds[rg * 4 + r][wn0 + nt * 16 + m16] = f2bf(v);
            }
        __syncthreads();

#pragma unroll
        for (int kt = 0; kt < 4; ++kt)
            af[kt] = *reinterpret_cast<const short8v*>(&t_lds[m16][kt * 32 + rg * 8]);
        float4v acc2[2];
#pragma unroll
        for (int nt = 0; nt < 2; ++nt) {
            acc2[nt] = (float4v){0.f, 0.f, 0.f, 0.f};
#pragma unroll
            for (int kt = 0; kt < 4; ++kt)
                acc2[nt] = __builtin_amdgcn_mfma_f32_16x16x32_bf16(af[kt], b2f[kt][nt], acc2[nt], 0, 0, 0);
        }

#pragma unroll
        for (int nt = 0; nt < 2; ++nt)
#pragma unroll
            for (int r = 0; r < 4; ++r) {
                const int node = nb + rg * 4 + r;
                if (node < N) {
                    float o = acc2[nt][r] + bias2[nt];
                    if (FINAL_RELU) o = fmaxf(o, 0.f);
                    out[(size_t)node * NDIM + wn0 + nt * 16 + m16] = o;
                    if (STATS) { ss[nt] += o; sq[nt] += o * o; }
                }
            }
    }

    if (STATS) {
#pragma unroll
        for (int nt = 0; nt < 2; ++nt) {
            float s = ss[nt], q = sq[nt];
            s += __shfl_xor(s, 16); q += __shfl_xor(q, 16);
            s += __shfl_xor(s, 32); q += __shfl_xor(q, 32);
            if (rg == 0) {
                atomicAdd(&stats[wn0 + nt * 16 + m16], s);
                atomicAdd(&stats[NDIM + wn0 + nt * 16 + m16], q);
            }
        }
    }
}

// ---------------------------------------------------------------------------
// BatchNorm apply (in place).
// ---------------------------------------------------------------------------
__global__ __launch_bounds__(256) void bn_apply(
    float* out,
    const float* __restrict__ stats,
    const float* __restrict__ gamma,
    const float* __restrict__ beta,
    int N)
{
    __shared__ float sc_s[NDIM];
    __shared__ float sh_s[NDIM];
    const float invN = 1.f / (float)N;
    if (threadIdx.x < NDIM) {
        const int f = threadIdx.x;
        const float mean = stats[f] * invN;
        const float var  = stats[NDIM + f] * invN - mean * mean;
        const float sc   = gamma[f] * rsqrtf(var + BN_EPS);
        sc_s[f] = sc;
        sh_s[f] = beta[f] - mean * sc;
    }
    __syncthreads();

    const int total4 = N * (NDIM / 4);
    float4* o4 = reinterpret_cast<float4*>(out);
    for (int idx = blockIdx.x * blockDim.x + threadIdx.x; idx < total4;
         idx += gridDim.x * blockDim.x) {
        const int fb = (idx & 31) * 4;
        float4 p = o4[idx];
        p.x = p.x * sc_s[fb + 0] + sh_s[fb + 0];
        p.y = p.y * sc_s[fb + 1] + sh_s[fb + 1];
        p.z = p.z * sc_s[fb + 2] + sh_s[fb + 2];
        p.w = p.w * sc_s[fb + 3] + sh_s[fb + 3];
        o4[idx] = p;
    }
}

// ---------------------------------------------------------------------------
extern "C" void kernel_launch(void* const* d_in, const int* in_sizes, int n_in,
                              void* d_out, int out_size, void* d_ws, size_t ws_size,
                              hipStream_t stream)
{
    const float* x    = (const float*)d_in[0];
    const int*   ei   = (const int*)  d_in[1];
    const float* ea   = (const float*)d_in[2];
    const float* We1  = (const float*)d_in[3];
    const float* be1  = (const float*)d_in[4];
    const float* W1   = (const float*)d_in[5];
    const float* b1   = (const float*)d_in[6];
    const float* W2   = (const float*)d_in[7];
    const float* b2   = (const float*)d_in[8];
    const float* We2  = (const float*)d_in[9];
    const float* be2  = (const float*)d_in[10];
    const float* W3   = (const float*)d_in[11];
    const float* b3   = (const float*)d_in[12];
    const float* W4   = (const float*)d_in[13];
    const float* b4   = (const float*)d_in[14];
    const float* gamma = (const float*)d_in[15];
    const float* beta  = (const float*)d_in[16];

    const int N = in_sizes[0] / NDIM;
    const int E = in_sizes[1] / 2;

    // workspace layout (aggr first; all 16B-aligned)
    float*          aggr   = (float*)d_ws;                            // [N*128]
    unsigned short* WeT1   = (unsigned short*)(aggr + (size_t)N * NDIM);
    unsigned short* WeT2   = WeT1 + NDIM * EDIM;
    unsigned short* W1T    = WeT2 + NDIM * EDIM;                      // [128*128]
    unsigned short* W2T    = W1T + NDIM * NDIM;
    unsigned short* W3T    = W2T + NDIM * NDIM;
    unsigned short* W4T    = W3T + NDIM * NDIM;
    int*            rowptr = (int*)(W4T + NDIM * NDIM);               // [N+1]
    int*            cursor = rowptr + (N + 1);                        // [N]
    int*            srcp   = cursor + N;                              // [E]
    int*            eidp   = srcp + E;                                // [E]
    int*            dstp   = eidp + E;                                // [E]
    float*          stats  = (float*)(dstp + E);                      // [256]
    float*          h      = (float*)d_out;

    hipMemsetAsync(cursor, 0, (size_t)N * sizeof(int), stream);
    hipMemsetAsync(stats, 0, 2 * NDIM * sizeof(float), stream);

    // ---- CSR build + weight prep ----
    hist_k<<<(E + 255) / 256, 256, 0, stream>>>(ei, cursor, E);
    scan_build<<<1, 1024, 0, stream>>>(cursor, rowptr, N);
    scatter_k<<<(E + 255) / 256, 256, 0, stream>>>(ei, cursor, srcp, eidp, dstp, E);
    prep_all<<<NDIM, NDIM, 0, stream>>>(We1, We2, W1, W2, W3, W4,
                                        WeT1, WeT2, W1T, W2T, W3T, W4T);

    const int egrid = 1024;   // persistent: 4 blocks/CU target
    const int mgrid = 625;

    // ---- conv1 ----
    hipMemsetAsync(aggr, 0, (size_t)N * NDIM * sizeof(float), stream);
    edge_mfma<<<egrid, 256, 0, stream>>>(x, ea, srcp, eidp, dstp, WeT1, be1, aggr, E);
    node_mlp_mfma<true, false><<<mgrid, 256, 0, stream>>>(x, aggr, W1T, b1, W2T, b2,
                                                          h, nullptr, N);
    // ---- conv2 ----
    hipMemsetAsync(aggr, 0, (size_t)N * NDIM * sizeof(float), stream);
    edge_mfma<<<egrid, 256, 0, stream>>>(h, ea, srcp, eidp, dstp, WeT2, be2, aggr, E);
    node_mlp_mfma<false, true><<<mgrid, 256, 0, stream>>>(h, aggr, W3T, b3, W4T, b4,
                                                          h, stats, N);
    // ---- batch norm ----
    bn_apply<<<1024, 256, 0, stream>>>(h, stats, gamma, beta, N);
}

// Round 9
// 444.075 us; speedup vs baseline: 1.2158x; 1.2158x over previous
//
#include <hip/hip_runtime.h>

#define NDIM 128
#define EDIM 64
#define BN_EPS 1e-5f
#define SPAN 64          // slots per wave (edge pass)
#define WPB  4           // waves per block (edge pass)
#define LPAD (NDIM + 4)  // edge-pass msg row pitch (f32)
#define PITCH 136        // node-mlp LDS row pitch in shorts

typedef __attribute__((ext_vector_type(8))) short short8v;
typedef __attribute__((ext_vector_type(4))) float float4v;

static __device__ __forceinline__ unsigned short f2bf(float f) {
    union { float f; unsigned u; } c; c.f = f;
    const unsigned r = (c.u + 0x7fffu + ((c.u >> 16) & 1u)) >> 16;
    return (unsigned short)r;
}

static __device__ __forceinline__ short8v pack_bf(const float4 f0, const float4 f1) {
    short8v a;
    a[0] = (short)f2bf(f0.x); a[1] = (short)f2bf(f0.y);
    a[2] = (short)f2bf(f0.z); a[3] = (short)f2bf(f0.w);
    a[4] = (short)f2bf(f1.x); a[5] = (short)f2bf(f1.y);
    a[6] = (short)f2bf(f1.z); a[7] = (short)f2bf(f1.w);
    return a;
}

static __device__ __forceinline__ short8v cvt_row(const float* __restrict__ arow, int k0) {
    const float4 f0 = *reinterpret_cast<const float4*>(arow + k0);
    const float4 f1 = *reinterpret_cast<const float4*>(arow + k0 + 4);
    return pack_bf(f0, f1);
}

// ---------------------------------------------------------------------------
// CSR build step 1: degree histogram over dst.
// ---------------------------------------------------------------------------
__global__ __launch_bounds__(256) void hist_k(
    const int* __restrict__ ei, int* __restrict__ deg, int E)
{
    const int e = blockIdx.x * blockDim.x + threadIdx.x;
    if (e < E) atomicAdd(&deg[ei[E + e]], 1);
}

// ---------------------------------------------------------------------------
// CSR build step 2: exclusive scan of deg -> rowptr + cursor.
// ---------------------------------------------------------------------------
__global__ __launch_bounds__(1024) void scan_build(
    int* __restrict__ cursor, int* __restrict__ rowptr, int N)
{
    __shared__ int wsums[16];
    __shared__ int run_s;
    const int tid  = threadIdx.x;
    const int lane = tid & 63;
    const int w    = tid >> 6;
    if (tid == 0) run_s = 0;
    __syncthreads();
    for (int base = 0; base < N; base += 1024) {
        const int i = base + tid;
        const int v = (i < N) ? cursor[i] : 0;
        int incl = v;
#pragma unroll
        for (int off = 1; off < 64; off <<= 1) {
            int t = __shfl_up(incl, off, 64);
            if (lane >= off) incl += t;
        }
        if (lane == 63) wsums[w] = incl;
        __syncthreads();
        if (w == 0) {
            int s = (lane < 16) ? wsums[lane] : 0;
#pragma unroll
            for (int off = 1; off < 16; off <<= 1) {
                int t = __shfl_up(s, off, 64);
                if (lane >= off) s += t;
            }
            if (lane < 16) wsums[lane] = s;
        }
        __syncthreads();
        const int waveoff = (w > 0) ? wsums[w - 1] : 0;
        const int run = run_s;
        const int excl = run + waveoff + incl - v;
        if (i < N) { rowptr[i] = excl; cursor[i] = excl; }
        __syncthreads();
        if (tid == 0) run_s += wsums[15];
        __syncthreads();
    }
    if (tid == 0) rowptr[N] = run_s;
}

// ---------------------------------------------------------------------------
// CSR build step 3: scatter src / edge-id / dst into slot order.
// ---------------------------------------------------------------------------
__global__ __launch_bounds__(256) void scatter_k(
    const int* __restrict__ ei, int* __restrict__ cursor,
    int* __restrict__ srcp, int* __restrict__ eidp, int* __restrict__ dstp, int E)
{
    const int e = blockIdx.x * blockDim.x + threadIdx.x;
    if (e < E) {
        const int d = ei[E + e];
        const int p = atomicAdd(&cursor[d], 1);
        srcp[p] = ei[e];
        eidp[p] = e;
        dstp[p] = d;
    }
}

// ---------------------------------------------------------------------------
// Weight prep (merged): We1/We2 -> [128][64] bf16T; W1..W4 -> [128][128] bf16T.
// ---------------------------------------------------------------------------
__global__ __launch_bounds__(128) void prep_all(
    const float* __restrict__ We1, const float* __restrict__ We2,
    const float* __restrict__ W1, const float* __restrict__ W2,
    const float* __restrict__ W3, const float* __restrict__ W4,
    unsigned short* __restrict__ WeT1, unsigned short* __restrict__ WeT2,
    unsigned short* __restrict__ W1T, unsigned short* __restrict__ W2T,
    unsigned short* __restrict__ W3T, unsigned short* __restrict__ W4T)
{
    const int c = blockIdx.x;    // 0..127 output column
    const int k = threadIdx.x;   // 0..127
    if (k < EDIM) {
        WeT1[c * EDIM + k] = f2bf(We1[k * NDIM + c]);
        WeT2[c * EDIM + k] = f2bf(We2[k * NDIM + c]);
    }
    W1T[c * NDIM + k] = f2bf(W1[k * NDIM + c]);
    W2T[c * NDIM + k] = f2bf(W2[k * NDIM + c]);
    W3T[c * NDIM + k] = f2bf(W3[k * NDIM + c]);
    W4T[c * NDIM + k] = f2bf(W4[k * NDIM + c]);
}

// ---------------------------------------------------------------------------
// Edge pass: MFMA + software-pipelined segmented accumulate (round-7 grid /
// span structure). NEW: ea rows prefetched as RAW float4 registers TWO tiles
// ahead; bf16 pack deferred to just before the MFMA, so no phase waits on
// memory issued in the same iteration.
// ---------------------------------------------------------------------------
__global__ __launch_bounds__(256) void edge_mfma(
    const float* __restrict__ xnode,          // [N,128]
    const float* __restrict__ ea,             // [E,64] edge order
    const int*   __restrict__ srcp,           // [E] slot-ordered src
    const int*   __restrict__ eidp,           // [E] slot-ordered edge id
    const int*   __restrict__ dstp,           // [E] slot-ordered dst (sorted)
    const unsigned short* __restrict__ WeT,   // [128][64] bf16
    const float* __restrict__ be,             // [128]
    float*       __restrict__ aggr,           // [N,128] pre-zeroed
    int E)
{
    __shared__ float msg[WPB][16][LPAD];

    const int tid   = threadIdx.x;
    const int lane  = tid & 63;
    const int wv    = tid >> 6;
    const int span0 = (blockIdx.x * WPB + wv) * SPAN;
    if (span0 >= E) return;

    const int m16 = lane & 15;   // A row (slot-within-tile) / C col-within-ntile
    const int kg  = lane >> 4;   // k-group 0..3
    const int k0a = kg * 8;

    // B fragments: full We resident (2 k-tiles x 8 n-tiles = 64 VGPR)
    short8v bfrag[2][8];
#pragma unroll
    for (int kk = 0; kk < 2; ++kk)
#pragma unroll
        for (int nt = 0; nt < 8; ++nt) {
            const int col = nt * 16 + m16;
            bfrag[kk][nt] = *reinterpret_cast<const short8v*>(&WeT[col * EDIM + kk * 32 + k0a]);
        }

    const int c0 = lane, c1 = lane + 64;
    const float be0 = be[c0], be1 = be[c1];
    float* msgw = &msg[wv][0][0];

    float a0 = 0.f, a1 = 0.f;

    if (span0 + SPAN <= E) {
        // ================= fast path (full span) =================
        int   sr_c[16], ds_c[16];
        float xv0_c[16], xv1_c[16];
        float4 eaf_n[4];   // raw ea for tile t+1 (2 ktiles x 2 float4)
        float4 eaf_nn[4];  // raw ea for tile t+2

        // ---- prologue: tile 0 fully (stall once), tile 1 raw ea in flight ----
#pragma unroll
        for (int s = 0; s < 16; ++s) { sr_c[s] = srcp[span0 + s]; ds_c[s] = dstp[span0 + s]; }
#pragma unroll
        for (int s = 0; s < 16; ++s) {
            xv0_c[s] = xnode[(long)sr_c[s] * NDIM + c0];
            xv1_c[s] = xnode[(long)sr_c[s] * NDIM + c1];
        }
        {
            const float* arow = ea + (long)eidp[span0 + m16] * EDIM;
            short8v af0 = cvt_row(arow, k0a);
            short8v af1 = cvt_row(arow, 32 + k0a);
#pragma unroll
            for (int nt = 0; nt < 8; ++nt) {
                float4v acc = (float4v){0.f, 0.f, 0.f, 0.f};
                acc = __builtin_amdgcn_mfma_f32_16x16x32_bf16(af0, bfrag[0][nt], acc, 0, 0, 0);
                acc = __builtin_amdgcn_mfma_f32_16x16x32_bf16(af1, bfrag[1][nt], acc, 0, 0, 0);
#pragma unroll
                for (int r = 0; r < 4; ++r)
                    msgw[(kg * 4 + r) * LPAD + nt * 16 + m16] = acc[r];
            }
        }
        {
            const float* arow = ea + (long)eidp[span0 + 16 + m16] * EDIM;
            eaf_n[0] = *reinterpret_cast<const float4*>(arow + k0a);
            eaf_n[1] = *reinterpret_cast<const float4*>(arow + k0a + 4);
            eaf_n[2] = *reinterpret_cast<const float4*>(arow + 32 + k0a);
            eaf_n[3] = *reinterpret_cast<const float4*>(arow + 32 + k0a + 4);
        }

        int dcur = ds_c[0];

#pragma unroll
        for (int t = 0; t < SPAN / 16; ++t) {
            const int base = span0 + t * 16;
            const bool hn  = (t + 1 < SPAN / 16);
            const bool hnn = (t + 2 < SPAN / 16);
            int   sr_n[16], ds_n[16];
            float xv0_n[16], xv1_n[16];

            // ---- phase 1: scalars + x rows for tile t+1 ----
            if (hn) {
#pragma unroll
                for (int s = 0; s < 16; ++s) {
                    sr_n[s] = srcp[base + 16 + s];
                    ds_n[s] = dstp[base + 16 + s];
                }
#pragma unroll
                for (int s = 0; s < 16; ++s) {
                    xv0_n[s] = xnode[(long)sr_n[s] * NDIM + c0];
                    xv1_n[s] = xnode[(long)sr_n[s] * NDIM + c1];
                }
            }

            // ---- phase 2: raw ea loads for tile t+2 (no consumption here) ----
            if (hnn) {
                const float* arow = ea + (long)eidp[base + 32 + m16] * EDIM;
                eaf_nn[0] = *reinterpret_cast<const float4*>(arow + k0a);
                eaf_nn[1] = *reinterpret_cast<const float4*>(arow + k0a + 4);
                eaf_nn[2] = *reinterpret_cast<const float4*>(arow + 32 + k0a);
                eaf_nn[3] = *reinterpret_cast<const float4*>(arow + 32 + k0a + 4);
            }

            // ---- phase 3: flush tile t (registers + LDS only) ----
#pragma unroll
            for (int s = 0; s < 16; ++s) {
                if (ds_c[s] != dcur) {
                    atomicAdd(&aggr[(long)dcur * NDIM + c0], a0);
                    atomicAdd(&aggr[(long)dcur * NDIM + c1], a1);
                    a0 = 0.f; a1 = 0.f; dcur = ds_c[s];
                }
                a0 += fmaxf(xv0_c[s] + msgw[s * LPAD + c0] + be0, 0.f);
                a1 += fmaxf(xv1_c[s] + msgw[s * LPAD + c1] + be1, 0.f);
            }

            // ---- phase 4: pack (data loaded >=1 iter ago) + MFMA tile t+1 ----
            if (hn) {
                const short8v af0 = pack_bf(eaf_n[0], eaf_n[1]);
                const short8v af1 = pack_bf(eaf_n[2], eaf_n[3]);
#pragma unroll
                for (int nt = 0; nt < 8; ++nt) {
                    float4v acc = (float4v){0.f, 0.f, 0.f, 0.f};
                    acc = __builtin_amdgcn_mfma_f32_16x16x32_bf16(af0, bfrag[0][nt], acc, 0, 0, 0);
                    acc = __builtin_amdgcn_mfma_f32_16x16x32_bf16(af1, bfrag[1][nt], acc, 0, 0, 0);
#pragma unroll
                    for (int r = 0; r < 4; ++r)
                        msgw[(kg * 4 + r) * LPAD + nt * 16 + m16] = acc[r];
                }
                // rotate pipeline
#pragma unroll
                for (int i = 0; i < 4; ++i) eaf_n[i] = eaf_nn[i];
#pragma unroll
                for (int s = 0; s < 16; ++s) {
                    sr_c[s] = sr_n[s]; ds_c[s] = ds_n[s];
                    xv0_c[s] = xv0_n[s]; xv1_c[s] = xv1_n[s];
                }
            }
        }
        atomicAdd(&aggr[(long)dcur * NDIM + c0], a0);
        atomicAdd(&aggr[(long)dcur * NDIM + c1], a1);
    } else {
        // ================= tail slow path (round-5 structure) =================
        const int spanEnd = E;
        int dcur = dstp[span0];
        for (int t = 0; t < SPAN / 16; ++t) {
            const int base = span0 + t * 16;
            if (base >= spanEnd) break;

            const int  slot = (base + m16 < E) ? base + m16 : E - 1;
            const float* arow = ea + (long)eidp[slot] * EDIM;
            short8v afrag[2];
            afrag[0] = cvt_row(arow, k0a);
            afrag[1] = cvt_row(arow, 32 + k0a);

#pragma unroll
            for (int nt = 0; nt < 8; ++nt) {
                float4v acc = (float4v){0.f, 0.f, 0.f, 0.f};
                acc = __builtin_amdgcn_mfma_f32_16x16x32_bf16(afrag[0], bfrag[0][nt], acc, 0, 0, 0);
                acc = __builtin_amdgcn_mfma_f32_16x16x32_bf16(afrag[1], bfrag[1][nt], acc, 0, 0, 0);
#pragma unroll
                for (int r = 0; r < 4; ++r)
                    msgw[(kg * 4 + r) * LPAD + nt * 16 + m16] = acc[r];
            }

            for (int s = 0; s < 16; ++s) {
                const int gs = base + s;
                if (gs >= spanEnd) break;
                const int d  = dstp[gs];
                const int sr = srcp[gs];
                if (d != dcur) {
                    atomicAdd(&aggr[(long)dcur * NDIM + c0], a0);
                    atomicAdd(&aggr[(long)dcur * NDIM + c1], a1);
                    a0 = 0.f; a1 = 0.f; dcur = d;
                }
                const float xv0 = xnode[(long)sr * NDIM + c0];
                const float xv1 = xnode[(long)sr * NDIM + c1];
                a0 += fmaxf(xv0 + msgw[s * LPAD + c0] + be0, 0.f);
                a1 += fmaxf(xv1 + msgw[s * LPAD + c1] + be1, 0.f);
            }
        }
        atomicAdd(&aggr[(long)dcur * NDIM + c0], a0);
        atomicAdd(&aggr[(long)dcur * NDIM + c1], a1);
    }
}

// ---------------------------------------------------------------------------
// Node MLP via MFMA (round-7, kept).
// ---------------------------------------------------------------------------
template <bool FINAL_RELU, bool STATS>
__global__ __launch_bounds__(256) void node_mlp_mfma(
    const float* xin,                    // may alias out (same-row read->write)
    const float* __restrict__ aggr,
    const unsigned short* __restrict__ W1T, const float* __restrict__ b1,
    const unsigned short* __restrict__ W2T, const float* __restrict__ b2,
    float* out,
    float* __restrict__ stats,
    int N)
{
    __shared__ unsigned short in_lds[16][PITCH];
    __shared__ unsigned short t_lds[16][PITCH];

    const int tid  = threadIdx.x;
    const int lane = tid & 63;
    const int wv   = tid >> 6;
    const int wn0  = wv * 32;
    const int m16  = lane & 15;
    const int rg   = lane >> 4;

    short8v b1f[4][2], b2f[4][2];
#pragma unroll
    for (int kt = 0; kt < 4; ++kt)
#pragma unroll
        for (int nt = 0; nt < 2; ++nt) {
            const int col = wn0 + nt * 16 + m16;
            b1f[kt][nt] = *reinterpret_cast<const short8v*>(&W1T[col * NDIM + kt * 32 + rg * 8]);
            b2f[kt][nt] = *reinterpret_cast<const short8v*>(&W2T[col * NDIM + kt * 32 + rg * 8]);
        }
    float bias1[2], bias2[2];
#pragma unroll
    for (int nt = 0; nt < 2; ++nt) {
        bias1[nt] = b1[wn0 + nt * 16 + m16];
        bias2[nt] = b2[wn0 + nt * 16 + m16];
    }

    float ss[2] = {0.f, 0.f}, sq[2] = {0.f, 0.f};

    const int ntile = (N + 15) >> 4;
    for (int tile = blockIdx.x; tile < ntile; tile += gridDim.x) {
        const int nb = tile << 4;

        {
            const int row = tid >> 4;
            const int ch  = tid & 15;
            const int gr  = nb + row;
            short8v pk = (short8v){0, 0, 0, 0, 0, 0, 0, 0};
            if (gr < N) {
                const float4* xp = reinterpret_cast<const float4*>(xin  + (size_t)gr * NDIM + ch * 8);
                const float4* ap = reinterpret_cast<const float4*>(aggr + (size_t)gr * NDIM + ch * 8);
                const float4 x0 = xp[0], x1 = xp[1];
                const float4 g0 = ap[0], g1 = ap[1];
                pk[0] = (short)f2bf(x0.x + g0.x); pk[1] = (short)f2bf(x0.y + g0.y);
                pk[2] = (short)f2bf(x0.z + g0.z); pk[3] = (short)f2bf(x0.w + g0.w);
                pk[4] = (short)f2bf(x1.x + g1.x); pk[5] = (short)f2bf(x1.y + g1.y);
                pk[6] = (short)f2bf(x1.z + g1.z); pk[7] = (short)f2bf(x1.w + g1.w);
            }
            *reinterpret_cast<short8v*>(&in_lds[row][ch * 8]) = pk;
        }
        __syncthreads();

        short8v af[4];
#pragma unroll
        for (int kt = 0; kt < 4; ++kt)
            af[kt] = *reinterpret_cast<const short8v*>(&in_lds[m16][kt * 32 + rg * 8]);
        float4v acc[2];
#pragma unroll
        for (int nt = 0; nt < 2; ++nt) {
            acc[nt] = (float4v){0.f, 0.f, 0.f, 0.f};
#pragma unroll
            for (int kt = 0; kt < 4; ++kt)
                acc[nt] = __builtin_amdgcn_mfma_f32_16x16x32_bf16(af[kt], b1f[kt][nt], acc[nt], 0, 0, 0);
        }
#pragma unroll
        for (int nt = 0; nt < 2; ++nt)
#pragma unroll
            for (int r = 0; r < 4; ++r) {
                const float v = fmaxf(acc[nt][r] + bias1[nt], 0.f);
                t_lds[rg * 4 + r][wn0 + nt * 16 + m16] = f2bf(v);
            }
        __syncthreads();

#pragma unroll
        for (int kt = 0; kt < 4; ++kt)
            af[kt] = *reinterpret_cast<const short8v*>(&t_lds[m16][kt * 32 + rg * 8]);
        float4v acc2[2];
#pragma unroll
        for (int nt = 0; nt < 2; ++nt) {
            acc2[nt] = (float4v){0.f, 0.f, 0.f, 0.f};
#pragma unroll
            for (int kt = 0; kt < 4; ++kt)
                acc2[nt] = __builtin_amdgcn_mfma_f32_16x16x32_bf16(af[kt], b2f[kt][nt], acc2[nt], 0, 0, 0);
        }

#pragma unroll
        for (int nt = 0; nt < 2; ++nt)
#pragma unroll
            for (int r = 0; r < 4; ++r) {
                const int node = nb + rg * 4 + r;
                if (node < N) {
                    float o = acc2[nt][r] + bias2[nt];
                    if (FINAL_RELU) o = fmaxf(o, 0.f);
                    out[(size_t)node * NDIM + wn0 + nt * 16 + m16] = o;
                    if (STATS) { ss[nt] += o; sq[nt] += o * o; }
                }
            }
    }

    if (STATS) {
#pragma unroll
        for (int nt = 0; nt < 2; ++nt) {
            float s = ss[nt], q = sq[nt];
            s += __shfl_xor(s, 16); q += __shfl_xor(q, 16);
            s += __shfl_xor(s, 32); q += __shfl_xor(q, 32);
            if (rg == 0) {
                atomicAdd(&stats[wn0 + nt * 16 + m16], s);
                atomicAdd(&stats[NDIM + wn0 + nt * 16 + m16], q);
            }
        }
    }
}

// ---------------------------------------------------------------------------
// BatchNorm apply (in place).
// ---------------------------------------------------------------------------
__global__ __launch_bounds__(256) void bn_apply(
    float* out,
    const float* __restrict__ stats,
    const float* __restrict__ gamma,
    const float* __restrict__ beta,
    int N)
{
    __shared__ float sc_s[NDIM];
    __shared__ float sh_s[NDIM];
    const float invN = 1.f / (float)N;
    if (threadIdx.x < NDIM) {
        const int f = threadIdx.x;
        const float mean = stats[f] * invN;
        const float var  = stats[NDIM + f] * invN - mean * mean;
        const float sc   = gamma[f] * rsqrtf(var + BN_EPS);
        sc_s[f] = sc;
        sh_s[f] = beta[f] - mean * sc;
    }
    __syncthreads();

    const int total4 = N * (NDIM / 4);
    float4* o4 = reinterpret_cast<float4*>(out);
    for (int idx = blockIdx.x * blockDim.x + threadIdx.x; idx < total4;
         idx += gridDim.x * blockDim.x) {
        const int fb = (idx & 31) * 4;
        float4 p = o4[idx];
        p.x = p.x * sc_s[fb + 0] + sh_s[fb + 0];
        p.y = p.y * sc_s[fb + 1] + sh_s[fb + 1];
        p.z = p.z * sc_s[fb + 2] + sh_s[fb + 2];
        p.w = p.w * sc_s[fb + 3] + sh_s[fb + 3];
        o4[idx] = p;
    }
}

// ---------------------------------------------------------------------------
extern "C" void kernel_launch(void* const* d_in, const int* in_sizes, int n_in,
                              void* d_out, int out_size, void* d_ws, size_t ws_size,
                              hipStream_t stream)
{
    const float* x    = (const float*)d_in[0];
    const int*   ei   = (const int*)  d_in[1];
    const float* ea   = (const float*)d_in[2];
    const float* We1  = (const float*)d_in[3];
    const float* be1  = (const float*)d_in[4];
    const float* W1   = (const float*)d_in[5];
    const float* b1   = (const float*)d_in[6];
    const float* W2   = (const float*)d_in[7];
    const float* b2   = (const float*)d_in[8];
    const float* We2  = (const float*)d_in[9];
    const float* be2  = (const float*)d_in[10];
    const float* W3   = (const float*)d_in[11];
    const float* b3   = (const float*)d_in[12];
    const float* W4   = (const float*)d_in[13];
    const float* b4   = (const float*)d_in[14];
    const float* gamma = (const float*)d_in[15];
    const float* beta  = (const float*)d_in[16];

    const int N = in_sizes[0] / NDIM;
    const int E = in_sizes[1] / 2;

    // workspace layout (aggr first; all 16B-aligned)
    float*          aggr   = (float*)d_ws;                            // [N*128]
    unsigned short* WeT1   = (unsigned short*)(aggr + (size_t)N * NDIM);
    unsigned short* WeT2   = WeT1 + NDIM * EDIM;
    unsigned short* W1T    = WeT2 + NDIM * EDIM;                      // [128*128]
    unsigned short* W2T    = W1T + NDIM * NDIM;
    unsigned short* W3T    = W2T + NDIM * NDIM;
    unsigned short* W4T    = W3T + NDIM * NDIM;
    int*            rowptr = (int*)(W4T + NDIM * NDIM);               // [N+1]
    int*            cursor = rowptr + (N + 1);                        // [N]
    int*            srcp   = cursor + N;                              // [E]
    int*            eidp   = srcp + E;                                // [E]
    int*            dstp   = eidp + E;                                // [E]
    float*          stats  = (float*)(dstp + E);                      // [256]
    float*          h      = (float*)d_out;

    hipMemsetAsync(cursor, 0, (size_t)N * sizeof(int), stream);
    hipMemsetAsync(stats, 0, 2 * NDIM * sizeof(float), stream);

    // ---- CSR build + weight prep ----
    hist_k<<<(E + 255) / 256, 256, 0, stream>>>(ei, cursor, E);
    scan_build<<<1, 1024, 0, stream>>>(cursor, rowptr, N);
    scatter_k<<<(E + 255) / 256, 256, 0, stream>>>(ei, cursor, srcp, eidp, dstp, E);
    prep_all<<<NDIM, NDIM, 0, stream>>>(We1, We2, W1, W2, W3, W4,
                                        WeT1, WeT2, W1T, W2T, W3T, W4T);

    const int egrid = (E + WPB * SPAN - 1) / (WPB * SPAN);   // round-7 grid
    const int mgrid = 625;

    // ---- conv1 ----
    hipMemsetAsync(aggr, 0, (size_t)N * NDIM * sizeof(float), stream);
    edge_mfma<<<egrid, 256, 0, stream>>>(x, ea, srcp, eidp, dstp, WeT1, be1, aggr, E);
    node_mlp_mfma<true, false><<<mgrid, 256, 0, stream>>>(x, aggr, W1T, b1, W2T, b2,
                                                          h, nullptr, N);
    // ---- conv2 ----
    hipMemsetAsync(aggr, 0, (size_t)N * NDIM * sizeof(float), stream);
    edge_mfma<<<egrid, 256, 0, stream>>>(h, ea, srcp, eidp, dstp, WeT2, be2, aggr, E);
    node_mlp_mfma<false, true><<<mgrid, 256, 0, stream>>>(h, aggr, W3T, b3, W4T, b4,
                                                          h, stats, N);
    // ---- batch norm ----
    bn_apply<<<1024, 256, 0, stream>>>(h, stats, gamma, beta, N);
}

// Round 10
// 422.277 us; speedup vs baseline: 1.2786x; 1.0516x over previous
//
#include <hip/hip_runtime.h>

#define NDIM 128
#define EDIM 64
#define BN_EPS 1e-5f
#define SPAN 64          // slots per wave (edge pass)
#define WPB  4           // waves per block (edge pass)
#define LPAD (NDIM + 4)  // edge-pass msg row pitch (f32)
#define PITCH 136        // node-mlp LDS row pitch in shorts

typedef __attribute__((ext_vector_type(8))) short short8v;
typedef __attribute__((ext_vector_type(4))) short short4v;
typedef __attribute__((ext_vector_type(4))) float float4v;

static __device__ __forceinline__ unsigned short f2bf(float f) {
    union { float f; unsigned u; } c; c.f = f;
    const unsigned r = (c.u + 0x7fffu + ((c.u >> 16) & 1u)) >> 16;
    return (unsigned short)r;
}

static __device__ __forceinline__ short8v pack_bf(const float4 f0, const float4 f1) {
    short8v a;
    a[0] = (short)f2bf(f0.x); a[1] = (short)f2bf(f0.y);
    a[2] = (short)f2bf(f0.z); a[3] = (short)f2bf(f0.w);
    a[4] = (short)f2bf(f1.x); a[5] = (short)f2bf(f1.y);
    a[6] = (short)f2bf(f1.z); a[7] = (short)f2bf(f1.w);
    return a;
}

static __device__ __forceinline__ short8v cvt_row(const float* __restrict__ arow, int k0) {
    const float4 f0 = *reinterpret_cast<const float4*>(arow + k0);
    const float4 f1 = *reinterpret_cast<const float4*>(arow + k0 + 4);
    return pack_bf(f0, f1);
}

// ---------------------------------------------------------------------------
// CSR build step 1: degree histogram over dst.
// ---------------------------------------------------------------------------
__global__ __launch_bounds__(256) void hist_k(
    const int* __restrict__ ei, int* __restrict__ deg, int E)
{
    const int e = blockIdx.x * blockDim.x + threadIdx.x;
    if (e < E) atomicAdd(&deg[ei[E + e]], 1);
}

// ---------------------------------------------------------------------------
// CSR build step 2: exclusive scan of deg -> rowptr + cursor.
// ---------------------------------------------------------------------------
__global__ __launch_bounds__(1024) void scan_build(
    int* __restrict__ cursor, int* __restrict__ rowptr, int N)
{
    __shared__ int wsums[16];
    __shared__ int run_s;
    const int tid  = threadIdx.x;
    const int lane = tid & 63;
    const int w    = tid >> 6;
    if (tid == 0) run_s = 0;
    __syncthreads();
    for (int base = 0; base < N; base += 1024) {
        const int i = base + tid;
        const int v = (i < N) ? cursor[i] : 0;
        int incl = v;
#pragma unroll
        for (int off = 1; off < 64; off <<= 1) {
            int t = __shfl_up(incl, off, 64);
            if (lane >= off) incl += t;
        }
        if (lane == 63) wsums[w] = incl;
        __syncthreads();
        if (w == 0) {
            int s = (lane < 16) ? wsums[lane] : 0;
#pragma unroll
            for (int off = 1; off < 16; off <<= 1) {
                int t = __shfl_up(s, off, 64);
                if (lane >= off) s += t;
            }
            if (lane < 16) wsums[lane] = s;
        }
        __syncthreads();
        const int waveoff = (w > 0) ? wsums[w - 1] : 0;
        const int run = run_s;
        const int excl = run + waveoff + incl - v;
        if (i < N) { rowptr[i] = excl; cursor[i] = excl; }
        __syncthreads();
        if (tid == 0) run_s += wsums[15];
        __syncthreads();
    }
    if (tid == 0) rowptr[N] = run_s;
}

// ---------------------------------------------------------------------------
// CSR build step 3: scatter src/dst into slot order; record both mappings.
// ---------------------------------------------------------------------------
__global__ __launch_bounds__(256) void scatter_k(
    const int* __restrict__ ei, int* __restrict__ cursor,
    int* __restrict__ srcp, int* __restrict__ dstp,
    int* __restrict__ slotof, int* __restrict__ eidp, int E)
{
    const int e = blockIdx.x * blockDim.x + threadIdx.x;
    if (e < E) {
        const int d = ei[E + e];
        const int p = atomicAdd(&cursor[d], 1);
        srcp[p]   = ei[e];
        dstp[p]   = d;
        slotof[e] = p;
        eidp[p]   = e;
    }
}

// ---------------------------------------------------------------------------
// Permute edge_attr into slot order as bf16: eap[slotof[e]] = bf16(ea[e]).
// Sequential coalesced reads (edge order); 128B-row coalesced scattered
// writes (fire-and-forget). Wave handles 4 edges/iter: lane = (quad, j16).
// ---------------------------------------------------------------------------
__global__ __launch_bounds__(256) void permute_ea(
    const float* __restrict__ ea, const int* __restrict__ slotof,
    unsigned short* __restrict__ eap, int E)
{
    const int tid  = threadIdx.x;
    const int lane = tid & 63;
    const int wv   = tid >> 6;
    const int q    = lane >> 4;   // edge within quad
    const int j    = lane & 15;   // float4 index within row
    const int nw   = gridDim.x * 4;
    for (int g = blockIdx.x * 4 + wv; g * 4 < E; g += nw) {
        const int e = g * 4 + q;
        if (e < E) {
            const float4 v = *reinterpret_cast<const float4*>(ea + (size_t)e * EDIM + j * 4);
            short4v pk;
            pk[0] = (short)f2bf(v.x); pk[1] = (short)f2bf(v.y);
            pk[2] = (short)f2bf(v.z); pk[3] = (short)f2bf(v.w);
            const int sl = slotof[e];
            *reinterpret_cast<short4v*>(eap + (size_t)sl * EDIM + j * 4) = pk;
        }
    }
}

// ---------------------------------------------------------------------------
// Weight prep (merged): We1/We2 -> [128][64] bf16T; W1..W4 -> [128][128] bf16T.
// ---------------------------------------------------------------------------
__global__ __launch_bounds__(128) void prep_all(
    const float* __restrict__ We1, const float* __restrict__ We2,
    const float* __restrict__ W1, const float* __restrict__ W2,
    const float* __restrict__ W3, const float* __restrict__ W4,
    unsigned short* __restrict__ WeT1, unsigned short* __restrict__ WeT2,
    unsigned short* __restrict__ W1T, unsigned short* __restrict__ W2T,
    unsigned short* __restrict__ W3T, unsigned short* __restrict__ W4T)
{
    const int c = blockIdx.x;    // 0..127 output column
    const int k = threadIdx.x;   // 0..127
    if (k < EDIM) {
        WeT1[c * EDIM + k] = f2bf(We1[k * NDIM + c]);
        WeT2[c * EDIM + k] = f2bf(We2[k * NDIM + c]);
    }
    W1T[c * NDIM + k] = f2bf(W1[k * NDIM + c]);
    W2T[c * NDIM + k] = f2bf(W2[k * NDIM + c]);
    W3T[c * NDIM + k] = f2bf(W3[k * NDIM + c]);
    W4T[c * NDIM + k] = f2bf(W4[k * NDIM + c]);
}

// ---------------------------------------------------------------------------
// Edge pass: MFMA + software-pipelined segmented accumulate.
// PERM=true : A-fragments loaded sequentially from pre-permuted bf16 eap
//             (no indirection, no pack in the hot loop).
// PERM=false: round-9 fallback (random ea via eidp, raw-f32 prefetch+pack).
// ---------------------------------------------------------------------------
template <bool PERM>
__global__ __launch_bounds__(256) void edge_mfma(
    const float* __restrict__ xnode,          // [N,128]
    const float* __restrict__ ea,             // [E,64] edge order (fallback)
    const unsigned short* __restrict__ eap,   // [E,64] bf16 slot order (perm)
    const int*   __restrict__ srcp,           // [E] slot-ordered src
    const int*   __restrict__ eidp,           // [E] slot-ordered edge id
    const int*   __restrict__ dstp,           // [E] slot-ordered dst (sorted)
    const unsigned short* __restrict__ WeT,   // [128][64] bf16
    const float* __restrict__ be,             // [128]
    float*       __restrict__ aggr,           // [N,128] pre-zeroed
    int E)
{
    __shared__ float msg[WPB][16][LPAD];

    const int tid   = threadIdx.x;
    const int lane  = tid & 63;
    const int wv    = tid >> 6;
    const int span0 = (blockIdx.x * WPB + wv) * SPAN;
    if (span0 >= E) return;

    const int m16 = lane & 15;   // A row (slot-within-tile) / C col-within-ntile
    const int kg  = lane >> 4;   // k-group 0..3
    const int k0a = kg * 8;

    // B fragments: full We resident (2 k-tiles x 8 n-tiles = 64 VGPR)
    short8v bfrag[2][8];
#pragma unroll
    for (int kk = 0; kk < 2; ++kk)
#pragma unroll
        for (int nt = 0; nt < 8; ++nt) {
            const int col = nt * 16 + m16;
            bfrag[kk][nt] = *reinterpret_cast<const short8v*>(&WeT[col * EDIM + kk * 32 + k0a]);
        }

    const int c0 = lane, c1 = lane + 64;
    const float be0 = be[c0], be1 = be[c1];
    float* msgw = &msg[wv][0][0];

    float a0 = 0.f, a1 = 0.f;

    if (span0 + SPAN <= E) {
        // ================= fast path (full span) =================
        int   sr_c[16], ds_c[16];
        float xv0_c[16], xv1_c[16];
        short8v af_n[2];    // A-frags for tile t+1 (PERM path)
        short8v af_nn[2];   // A-frags for tile t+2 (PERM path)
        float4 eaf_n[4];    // raw ea tile t+1 (fallback path)
        float4 eaf_nn[4];   // raw ea tile t+2 (fallback path)

        // ---- prologue: tile 0 fully, tile 1 A-stream in flight ----
#pragma unroll
        for (int s = 0; s < 16; ++s) { sr_c[s] = srcp[span0 + s]; ds_c[s] = dstp[span0 + s]; }
#pragma unroll
        for (int s = 0; s < 16; ++s) {
            xv0_c[s] = xnode[(long)sr_c[s] * NDIM + c0];
            xv1_c[s] = xnode[(long)sr_c[s] * NDIM + c1];
        }
        {
            short8v af0, af1;
            if (PERM) {
                const unsigned short* arow = eap + (size_t)(span0 + m16) * EDIM;
                af0 = *reinterpret_cast<const short8v*>(arow + k0a);
                af1 = *reinterpret_cast<const short8v*>(arow + 32 + k0a);
            } else {
                const float* arow = ea + (long)eidp[span0 + m16] * EDIM;
                af0 = cvt_row(arow, k0a);
                af1 = cvt_row(arow, 32 + k0a);
            }
#pragma unroll
            for (int nt = 0; nt < 8; ++nt) {
                float4v acc = (float4v){0.f, 0.f, 0.f, 0.f};
                acc = __builtin_amdgcn_mfma_f32_16x16x32_bf16(af0, bfrag[0][nt], acc, 0, 0, 0);
                acc = __builtin_amdgcn_mfma_f32_16x16x32_bf16(af1, bfrag[1][nt], acc, 0, 0, 0);
#pragma unroll
                for (int r = 0; r < 4; ++r)
                    msgw[(kg * 4 + r) * LPAD + nt * 16 + m16] = acc[r];
            }
        }
        if (PERM) {
            const unsigned short* arow = eap + (size_t)(span0 + 16 + m16) * EDIM;
            af_n[0] = *reinterpret_cast<const short8v*>(arow + k0a);
            af_n[1] = *reinterpret_cast<const short8v*>(arow + 32 + k0a);
        } else {
            const float* arow = ea + (long)eidp[span0 + 16 + m16] * EDIM;
            eaf_n[0] = *reinterpret_cast<const float4*>(arow + k0a);
            eaf_n[1] = *reinterpret_cast<const float4*>(arow + k0a + 4);
            eaf_n[2] = *reinterpret_cast<const float4*>(arow + 32 + k0a);
            eaf_n[3] = *reinterpret_cast<const float4*>(arow + 32 + k0a + 4);
        }

        int dcur = ds_c[0];

#pragma unroll
        for (int t = 0; t < SPAN / 16; ++t) {
            const int base = span0 + t * 16;
            const bool hn  = (t + 1 < SPAN / 16);
            const bool hnn = (t + 2 < SPAN / 16);
            int   sr_n[16], ds_n[16];
            float xv0_n[16], xv1_n[16];

            // ---- phase 1: scalars + x rows for tile t+1 ----
            if (hn) {
#pragma unroll
                for (int s = 0; s < 16; ++s) {
                    sr_n[s] = srcp[base + 16 + s];
                    ds_n[s] = dstp[base + 16 + s];
                }
#pragma unroll
                for (int s = 0; s < 16; ++s) {
                    xv0_n[s] = xnode[(long)sr_n[s] * NDIM + c0];
                    xv1_n[s] = xnode[(long)sr_n[s] * NDIM + c1];
                }
            }

            // ---- phase 2: A-stream loads for tile t+2 ----
            if (hnn) {
                if (PERM) {
                    const unsigned short* arow = eap + (size_t)(base + 32 + m16) * EDIM;
                    af_nn[0] = *reinterpret_cast<const short8v*>(arow + k0a);
                    af_nn[1] = *reinterpret_cast<const short8v*>(arow + 32 + k0a);
                } else {
                    const float* arow = ea + (long)eidp[base + 32 + m16] * EDIM;
                    eaf_nn[0] = *reinterpret_cast<const float4*>(arow + k0a);
                    eaf_nn[1] = *reinterpret_cast<const float4*>(arow + k0a + 4);
                    eaf_nn[2] = *reinterpret_cast<const float4*>(arow + 32 + k0a);
                    eaf_nn[3] = *reinterpret_cast<const float4*>(arow + 32 + k0a + 4);
                }
            }

            // ---- phase 3: flush tile t (registers + LDS only) ----
#pragma unroll
            for (int s = 0; s < 16; ++s) {
                if (ds_c[s] != dcur) {
                    atomicAdd(&aggr[(long)dcur * NDIM + c0], a0);
                    atomicAdd(&aggr[(long)dcur * NDIM + c1], a1);
                    a0 = 0.f; a1 = 0.f; dcur = ds_c[s];
                }
                a0 += fmaxf(xv0_c[s] + msgw[s * LPAD + c0] + be0, 0.f);
                a1 += fmaxf(xv1_c[s] + msgw[s * LPAD + c1] + be1, 0.f);
            }

            // ---- phase 4: MFMA tile t+1 + rotate ----
            if (hn) {
                short8v af0, af1;
                if (PERM) { af0 = af_n[0]; af1 = af_n[1]; }
                else      { af0 = pack_bf(eaf_n[0], eaf_n[1]); af1 = pack_bf(eaf_n[2], eaf_n[3]); }
#pragma unroll
                for (int nt = 0; nt < 8; ++nt) {
                    float4v acc = (float4v){0.f, 0.f, 0.f, 0.f};
                    acc = __builtin_amdgcn_mfma_f32_16x16x32_bf16(af0, bfrag[0][nt], acc, 0, 0, 0);
                    acc = __builtin_amdgcn_mfma_f32_16x16x32_bf16(af1, bfrag[1][nt], acc, 0, 0, 0);
#pragma unroll
                    for (int r = 0; r < 4; ++r)
                        msgw[(kg * 4 + r) * LPAD + nt * 16 + m16] = acc[r];
                }
                if (PERM) {
                    af_n[0] = af_nn[0]; af_n[1] = af_nn[1];
                } else {
#pragma unroll
                    for (int i = 0; i < 4; ++i) eaf_n[i] = eaf_nn[i];
                }
#pragma unroll
                for (int s = 0; s < 16; ++s) {
                    sr_c[s] = sr_n[s]; ds_c[s] = ds_n[s];
                    xv0_c[s] = xv0_n[s]; xv1_c[s] = xv1_n[s];
                }
            }
        }
        atomicAdd(&aggr[(long)dcur * NDIM + c0], a0);
        atomicAdd(&aggr[(long)dcur * NDIM + c1], a1);
    } else {
        // ================= tail slow path =================
        const int spanEnd = E;
        int dcur = dstp[span0];
        for (int t = 0; t < SPAN / 16; ++t) {
            const int base = span0 + t * 16;
            if (base >= spanEnd) break;

            const int slot = (base + m16 < E) ? base + m16 : E - 1;
            short8v afrag[2];
            if (PERM) {
                const unsigned short* arow = eap + (size_t)slot * EDIM;
                afrag[0] = *reinterpret_cast<const short8v*>(arow + k0a);
                afrag[1] = *reinterpret_cast<const short8v*>(arow + 32 + k0a);
            } else {
                const float* arow = ea + (long)eidp[slot] * EDIM;
                afrag[0] = cvt_row(arow, k0a);
                afrag[1] = cvt_row(arow, 32 + k0a);
            }

#pragma unroll
            for (int nt = 0; nt < 8; ++nt) {
                float4v acc = (float4v){0.f, 0.f, 0.f, 0.f};
                acc = __builtin_amdgcn_mfma_f32_16x16x32_bf16(afrag[0], bfrag[0][nt], acc, 0, 0, 0);
                acc = __builtin_amdgcn_mfma_f32_16x16x32_bf16(afrag[1], bfrag[1][nt], acc, 0, 0, 0);
#pragma unroll
                for (int r = 0; r < 4; ++r)
                    msgw[(kg * 4 + r) * LPAD + nt * 16 + m16] = acc[r];
            }

            for (int s = 0; s < 16; ++s) {
                const int gs = base + s;
                if (gs >= spanEnd) break;
                const int d  = dstp[gs];
                const int sr = srcp[gs];
                if (d != dcur) {
                    atomicAdd(&aggr[(long)dcur * NDIM + c0], a0);
                    atomicAdd(&aggr[(long)dcur * NDIM + c1], a1);
                    a0 = 0.f; a1 = 0.f; dcur = d;
                }
                const float xv0 = xnode[(long)sr * NDIM + c0];
                const float xv1 = xnode[(long)sr * NDIM + c1];
                a0 += fmaxf(xv0 + msgw[s * LPAD + c0] + be0, 0.f);
                a1 += fmaxf(xv1 + msgw[s * LPAD + c1] + be1, 0.f);
            }
        }
        atomicAdd(&aggr[(long)dcur * NDIM + c0], a0);
        atomicAdd(&aggr[(long)dcur * NDIM + c1], a1);
    }
}

// ---------------------------------------------------------------------------
// Node MLP via MFMA (round-7, kept).
// ---------------------------------------------------------------------------
template <bool FINAL_RELU, bool STATS>
__global__ __launch_bounds__(256) void node_mlp_mfma(
    const float* xin,                    // may alias out (same-row read->write)
    const float* __restrict__ aggr,
    const unsigned short* __restrict__ W1T, const float* __restrict__ b1,
    const unsigned short* __restrict__ W2T, const float* __restrict__ b2,
    float* out,
    float* __restrict__ stats,
    int N)
{
    __shared__ unsigned short in_lds[16][PITCH];
    __shared__ unsigned short t_lds[16][PITCH];

    const int tid  = threadIdx.x;
    const int lane = tid & 63;
    const int wv   = tid >> 6;
    const int wn0  = wv * 32;
    const int m16  = lane & 15;
    const int rg   = lane >> 4;

    short8v b1f[4][2], b2f[4][2];
#pragma unroll
    for (int kt = 0; kt < 4; ++kt)
#pragma unroll
        for (int nt = 0; nt < 2; ++nt) {
            const int col = wn0 + nt * 16 + m16;
            b1f[kt][nt] = *reinterpret_cast<const short8v*>(&W1T[col * NDIM + kt * 32 + rg * 8]);
            b2f[kt][nt] = *reinterpret_cast<const short8v*>(&W2T[col * NDIM + kt * 32 + rg * 8]);
        }
    float bias1[2], bias2[2];
#pragma unroll
    for (int nt = 0; nt < 2; ++nt) {
        bias1[nt] = b1[wn0 + nt * 16 + m16];
        bias2[nt] = b2[wn0 + nt * 16 + m16];
    }

    float ss[2] = {0.f, 0.f}, sq[2] = {0.f, 0.f};

    const int ntile = (N + 15) >> 4;
    for (int tile = blockIdx.x; tile < ntile; tile += gridDim.x) {
        const int nb = tile << 4;

        {
            const int row = tid >> 4;
            const int ch  = tid & 15;
            const int gr  = nb + row;
            short8v pk = (short8v){0, 0, 0, 0, 0, 0, 0, 0};
            if (gr < N) {
                const float4* xp = reinterpret_cast<const float4*>(xin  + (size_t)gr * NDIM + ch * 8);
                const float4* ap = reinterpret_cast<const float4*>(aggr + (size_t)gr * NDIM + ch * 8);
                const float4 x0 = xp[0], x1 = xp[1];
                const float4 g0 = ap[0], g1 = ap[1];
                pk[0] = (short)f2bf(x0.x + g0.x); pk[1] = (short)f2bf(x0.y + g0.y);
                pk[2] = (short)f2bf(x0.z + g0.z); pk[3] = (short)f2bf(x0.w + g0.w);
                pk[4] = (short)f2bf(x1.x + g1.x); pk[5] = (short)f2bf(x1.y + g1.y);
                pk[6] = (short)f2bf(x1.z + g1.z); pk[7] = (short)f2bf(x1.w + g1.w);
            }
            *reinterpret_cast<short8v*>(&in_lds[row][ch * 8]) = pk;
        }
        __syncthreads();

        short8v af[4];
#pragma unroll
        for (int kt = 0; kt < 4; ++kt)
            af[kt] = *reinterpret_cast<const short8v*>(&in_lds[m16][kt * 32 + rg * 8]);
        float4v acc[2];
#pragma unroll
        for (int nt = 0; nt < 2; ++nt) {
            acc[nt] = (float4v){0.f, 0.f, 0.f, 0.f};
#pragma unroll
            for (int kt = 0; kt < 4; ++kt)
                acc[nt] = __builtin_amdgcn_mfma_f32_16x16x32_bf16(af[kt], b1f[kt][nt], acc[nt], 0, 0, 0);
        }
#pragma unroll
        for (int nt = 0; nt < 2; ++nt)
#pragma unroll
            for (int r = 0; r < 4; ++r) {
                const float v = fmaxf(acc[nt][r] + bias1[nt], 0.f);
                t_lds[rg * 4 + r][wn0 + nt * 16 + m16] = f2bf(v);
            }
        __syncthreads();

#pragma unroll
        for (int kt = 0; kt < 4; ++kt)
            af[kt] = *reinterpret_cast<const short8v*>(&t_lds[m16][kt * 32 + rg * 8]);
        float4v acc2[2];
#pragma unroll
        for (int nt = 0; nt < 2; ++nt) {
            acc2[nt] = (float4v){0.f, 0.f, 0.f, 0.f};
#pragma unroll
            for (int kt = 0; kt < 4; ++kt)
                acc2[nt] = __builtin_amdgcn_mfma_f32_16x16x32_bf16(af[kt], b2f[kt][nt], acc2[nt], 0, 0, 0);
        }

#pragma unroll
        for (int nt = 0; nt < 2; ++nt)
#pragma unroll
            for (int r = 0; r < 4; ++r) {
                const int node = nb + rg * 4 + r;
                if (node < N) {
                    float o = acc2[nt][r] + bias2[nt];
                    if (FINAL_RELU) o = fmaxf(o, 0.f);
                    out[(size_t)node * NDIM + wn0 + nt * 16 + m16] = o;
                    if (STATS) { ss[nt] += o; sq[nt] += o * o; }
                }
            }
    }

    if (STATS) {
#pragma unroll
        for (int nt = 0; nt < 2; ++nt) {
            float s = ss[nt], q = sq[nt];
            s += __shfl_xor(s, 16); q += __shfl_xor(q, 16);
            s += __shfl_xor(s, 32); q += __shfl_xor(q, 32);
            if (rg == 0) {
                atomicAdd(&stats[wn0 + nt * 16 + m16], s);
                atomicAdd(&stats[NDIM + wn0 + nt * 16 + m16], q);
            }
        }
    }
}

// ---------------------------------------------------------------------------
// BatchNorm apply (in place).
// ---------------------------------------------------------------------------
__global__ __launch_bounds__(256) void bn_apply(
    float* out,
    const float* __restrict__ stats,
    const float* __restrict__ gamma,
    const float* __restrict__ beta,
    int N)
{
    __shared__ float sc_s[NDIM];
    __shared__ float sh_s[NDIM];
    const float invN = 1.f / (float)N;
    if (threadIdx.x < NDIM) {
        const int f = threadIdx.x;
        const float mean = stats[f] * invN;
        const float var  = stats[NDIM + f] * invN - mean * mean;
        const float sc   = gamma[f] * rsqrtf(var + BN_EPS);
        sc_s[f] = sc;
        sh_s[f] = beta[f] - mean * sc;
    }
    __syncthreads();

    const int total4 = N * (NDIM / 4);
    float4* o4 = reinterpret_cast<float4*>(out);
    for (int idx = blockIdx.x * blockDim.x + threadIdx.x; idx < total4;
         idx += gridDim.x * blockDim.x) {
        const int fb = (idx & 31) * 4;
        float4 p = o4[idx];
        p.x = p.x * sc_s[fb + 0] + sh_s[fb + 0];
        p.y = p.y * sc_s[fb + 1] + sh_s[fb + 1];
        p.z = p.z * sc_s[fb + 2] + sh_s[fb + 2];
        p.w = p.w * sc_s[fb + 3] + sh_s[fb + 3];
        o4[idx] = p;
    }
}

// ---------------------------------------------------------------------------
extern "C" void kernel_launch(void* const* d_in, const int* in_sizes, int n_in,
                              void* d_out, int out_size, void* d_ws, size_t ws_size,
                              hipStream_t stream)
{
    const float* x    = (const float*)d_in[0];
    const int*   ei   = (const int*)  d_in[1];
    const float* ea   = (const float*)d_in[2];
    const float* We1  = (const float*)d_in[3];
    const float* be1  = (const float*)d_in[4];
    const float* W1   = (const float*)d_in[5];
    const float* b1   = (const float*)d_in[6];
    const float* W2   = (const float*)d_in[7];
    const float* b2   = (const float*)d_in[8];
    const float* We2  = (const float*)d_in[9];
    const float* be2  = (const float*)d_in[10];
    const float* W3   = (const float*)d_in[11];
    const float* b3   = (const float*)d_in[12];
    const float* W4   = (const float*)d_in[13];
    const float* b4   = (const float*)d_in[14];
    const float* gamma = (const float*)d_in[15];
    const float* beta  = (const float*)d_in[16];

    const int N = in_sizes[0] / NDIM;
    const int E = in_sizes[1] / 2;

    // workspace layout (aggr first; all 16B-aligned)
    float*          aggr   = (float*)d_ws;                            // [N*128]
    unsigned short* WeT1   = (unsigned short*)(aggr + (size_t)N * NDIM);
    unsigned short* WeT2   = WeT1 + NDIM * EDIM;
    unsigned short* W1T    = WeT2 + NDIM * EDIM;                      // [128*128]
    unsigned short* W2T    = W1T + NDIM * NDIM;
    unsigned short* W3T    = W2T + NDIM * NDIM;
    unsigned short* W4T    = W3T + NDIM * NDIM;
    int*            rowptr = (int*)(W4T + NDIM * NDIM);               // [N+1]
    int*            cursor = rowptr + (N + 1);                        // [N]
    int*            srcp   = cursor + N;                              // [E]
    int*            dstp   = srcp + E;                                // [E]
    int*            slotof = dstp + E;                                // [E]
    int*            eidp   = slotof + E;                              // [E]
    float*          stats  = (float*)(eidp + E);                      // [256]
    unsigned short* eap    = (unsigned short*)(stats + 2 * NDIM);     // [E*64] bf16

    const size_t need_perm = (size_t)((char*)eap - (char*)d_ws) + (size_t)E * EDIM * 2 + 64;
    const bool   perm      = ws_size >= need_perm;

    hipMemsetAsync(cursor, 0, (size_t)N * sizeof(int), stream);
    hipMemsetAsync(stats, 0, 2 * NDIM * sizeof(float), stream);

    // ---- CSR build + weight prep ----
    hist_k<<<(E + 255) / 256, 256, 0, stream>>>(ei, cursor, E);
    scan_build<<<1, 1024, 0, stream>>>(cursor, rowptr, N);
    scatter_k<<<(E + 255) / 256, 256, 0, stream>>>(ei, cursor, srcp, dstp, slotof, eidp, E);
    prep_all<<<NDIM, NDIM, 0, stream>>>(We1, We2, W1, W2, W3, W4,
                                        WeT1, WeT2, W1T, W2T, W3T, W4T);
    if (perm)
        permute_ea<<<1024, 256, 0, stream>>>(ea, slotof, eap, E);

    const int egrid = (E + WPB * SPAN - 1) / (WPB * SPAN);
    const int mgrid = 625;
    float* h = (float*)d_out;

    // ---- conv1 ----
    hipMemsetAsync(aggr, 0, (size_t)N * NDIM * sizeof(float), stream);
    if (perm)
        edge_mfma<true><<<egrid, 256, 0, stream>>>(x, ea, eap, srcp, eidp, dstp, WeT1, be1, aggr, E);
    else
        edge_mfma<false><<<egrid, 256, 0, stream>>>(x, ea, eap, srcp, eidp, dstp, WeT1, be1, aggr, E);
    node_mlp_mfma<true, false><<<mgrid, 256, 0, stream>>>(x, aggr, W1T, b1, W2T, b2,
                                                          h, nullptr, N);
    // ---- conv2 ----
    hipMemsetAsync(aggr, 0, (size_t)N * NDIM * sizeof(float), stream);
    if (perm)
        edge_mfma<true><<<egrid, 256, 0, stream>>>(h, ea, eap, srcp, eidp, dstp, WeT2, be2, aggr, E);
    else
        edge_mfma<false><<<egrid, 256, 0, stream>>>(h, ea, eap, srcp, eidp, dstp, WeT2, be2, aggr, E);
    node_mlp_mfma<false, true><<<mgrid, 256, 0, stream>>>(h, aggr, W3T, b3, W4T, b4,
                                                          h, stats, N);
    // ---- batch norm ----
    bn_apply<<<1024, 256, 0, stream>>>(h, stats, gamma, beta, N);
}

// Round 11
// 376.273 us; speedup vs baseline: 1.4349x; 1.1223x over previous
//
#include <hip/hip_runtime.h>

#define NDIM 128
#define EDIM 64
#define BN_EPS 1e-5f
#define SPAN 64          // slots per wave (edge pass)
#define WPB  4           // waves per block (edge pass)
#define LPAD (NDIM + 4)  // edge-pass msg row pitch (f32)
#define PITCH 136        // node-mlp LDS row pitch in shorts

typedef __attribute__((ext_vector_type(8))) short short8v;
typedef __attribute__((ext_vector_type(4))) short short4v;
typedef __attribute__((ext_vector_type(4))) float float4v;

static __device__ __forceinline__ unsigned short f2bf(float f) {
    union { float f; unsigned u; } c; c.f = f;
    const unsigned r = (c.u + 0x7fffu + ((c.u >> 16) & 1u)) >> 16;
    return (unsigned short)r;
}

static __device__ __forceinline__ short8v pack_bf(const float4 f0, const float4 f1) {
    short8v a;
    a[0] = (short)f2bf(f0.x); a[1] = (short)f2bf(f0.y);
    a[2] = (short)f2bf(f0.z); a[3] = (short)f2bf(f0.w);
    a[4] = (short)f2bf(f1.x); a[5] = (short)f2bf(f1.y);
    a[6] = (short)f2bf(f1.z); a[7] = (short)f2bf(f1.w);
    return a;
}

static __device__ __forceinline__ short8v cvt_row(const float* __restrict__ arow, int k0) {
    const float4 f0 = *reinterpret_cast<const float4*>(arow + k0);
    const float4 f1 = *reinterpret_cast<const float4*>(arow + k0 + 4);
    return pack_bf(f0, f1);
}

// ---------------------------------------------------------------------------
// CSR build step 1: degree histogram over dst.
// ---------------------------------------------------------------------------
__global__ __launch_bounds__(256) void hist_k(
    const int* __restrict__ ei, int* __restrict__ deg, int E)
{
    const int e = blockIdx.x * blockDim.x + threadIdx.x;
    if (e < E) atomicAdd(&deg[ei[E + e]], 1);
}

// ---------------------------------------------------------------------------
// CSR build step 2: exclusive scan of deg -> rowptr + cursor.
// 8 elements/thread (int4 x2), wave scan over thread sums, 7 iterations.
// ---------------------------------------------------------------------------
__global__ __launch_bounds__(1024) void scan_build(
    int* __restrict__ cursor, int* __restrict__ rowptr, int N)
{
    __shared__ int wsums[16];
    __shared__ int run_s;
    const int tid  = threadIdx.x;
    const int lane = tid & 63;
    const int w    = tid >> 6;
    if (tid == 0) run_s = 0;
    __syncthreads();
    for (int base = 0; base < N; base += 8192) {
        const int i0 = base + tid * 8;
        int v[8];
#pragma unroll
        for (int k = 0; k < 8; ++k) v[k] = 0;
        if (i0 + 7 < N) {
            const int4 a = *reinterpret_cast<const int4*>(cursor + i0);
            const int4 b = *reinterpret_cast<const int4*>(cursor + i0 + 4);
            v[0] = a.x; v[1] = a.y; v[2] = a.z; v[3] = a.w;
            v[4] = b.x; v[5] = b.y; v[6] = b.z; v[7] = b.w;
        } else if (i0 < N) {
            for (int k = 0; k < 8 && i0 + k < N; ++k) v[k] = cursor[i0 + k];
        }
        const int tsum = ((v[0] + v[1]) + (v[2] + v[3])) + ((v[4] + v[5]) + (v[6] + v[7]));
        int incl = tsum;
#pragma unroll
        for (int off = 1; off < 64; off <<= 1) {
            int t = __shfl_up(incl, off, 64);
            if (lane >= off) incl += t;
        }
        if (lane == 63) wsums[w] = incl;
        __syncthreads();
        if (w == 0) {
            int s = (lane < 16) ? wsums[lane] : 0;
#pragma unroll
            for (int off = 1; off < 16; off <<= 1) {
                int t = __shfl_up(s, off, 64);
                if (lane >= off) s += t;
            }
            if (lane < 16) wsums[lane] = s;
        }
        __syncthreads();
        const int waveoff = (w > 0) ? wsums[w - 1] : 0;
        int acc = run_s + waveoff + incl - tsum;   // exclusive prefix at i0
        if (i0 + 7 < N) {
            int4 ra, rb;
            ra.x = acc;            ra.y = acc + v[0];
            ra.z = ra.y + v[1];    ra.w = ra.z + v[2];
            rb.x = ra.w + v[3];    rb.y = rb.x + v[4];
            rb.z = rb.y + v[5];    rb.w = rb.z + v[6];
            *reinterpret_cast<int4*>(rowptr + i0) = ra;
            *reinterpret_cast<int4*>(rowptr + i0 + 4) = rb;
            *reinterpret_cast<int4*>(cursor + i0) = ra;
            *reinterpret_cast<int4*>(cursor + i0 + 4) = rb;
        } else if (i0 < N) {
            for (int k = 0; k < 8 && i0 + k < N; ++k) {
                rowptr[i0 + k] = acc; cursor[i0 + k] = acc; acc += v[k];
            }
        }
        __syncthreads();
        if (tid == 0) run_s += wsums[15];
        __syncthreads();
    }
    if (tid == 0) rowptr[N] = run_s;
}

// ---------------------------------------------------------------------------
// CSR build step 3: scatter src/dst into slot order + inverse map eidp.
// ---------------------------------------------------------------------------
__global__ __launch_bounds__(256) void scatter_k(
    const int* __restrict__ ei, int* __restrict__ cursor,
    int* __restrict__ srcp, int* __restrict__ dstp,
    int* __restrict__ eidp, int E)
{
    const int e = blockIdx.x * blockDim.x + threadIdx.x;
    if (e < E) {
        const int d = ei[E + e];
        const int p = atomicAdd(&cursor[d], 1);
        srcp[p] = ei[e];
        dstp[p] = d;
        eidp[p] = e;
    }
}

// ---------------------------------------------------------------------------
// Permute edge_attr into slot order as bf16 — GATHER form:
//   eap[p] = bf16(ea[eidp[p]])
// eidp read sequential; ea rows gathered (256B granules, largely L3-hit);
// eap written fully sequential/coalesced. 16 lanes per slot.
// ---------------------------------------------------------------------------
__global__ __launch_bounds__(256) void permute_ea(
    const float* __restrict__ ea, const int* __restrict__ eidp,
    unsigned short* __restrict__ eap, int E)
{
    const int tid  = threadIdx.x;
    const int sg   = tid >> 4;    // slot group within block (0..15)
    const int j    = tid & 15;    // float4 index within row
    const int step = gridDim.x * 16;
    for (int p = blockIdx.x * 16 + sg; p < E; p += step) {
        const int e = eidp[p];
        const float4 v = *reinterpret_cast<const float4*>(ea + (size_t)e * EDIM + j * 4);
        short4v pk;
        pk[0] = (short)f2bf(v.x); pk[1] = (short)f2bf(v.y);
        pk[2] = (short)f2bf(v.z); pk[3] = (short)f2bf(v.w);
        *reinterpret_cast<short4v*>(eap + (size_t)p * EDIM + j * 4) = pk;
    }
}

// ---------------------------------------------------------------------------
// Weight prep (merged): We1/We2 -> [128][64] bf16T; W1..W4 -> [128][128] bf16T.
// ---------------------------------------------------------------------------
__global__ __launch_bounds__(128) void prep_all(
    const float* __restrict__ We1, const float* __restrict__ We2,
    const float* __restrict__ W1, const float* __restrict__ W2,
    const float* __restrict__ W3, const float* __restrict__ W4,
    unsigned short* __restrict__ WeT1, unsigned short* __restrict__ WeT2,
    unsigned short* __restrict__ W1T, unsigned short* __restrict__ W2T,
    unsigned short* __restrict__ W3T, unsigned short* __restrict__ W4T)
{
    const int c = blockIdx.x;    // 0..127 output column
    const int k = threadIdx.x;   // 0..127
    if (k < EDIM) {
        WeT1[c * EDIM + k] = f2bf(We1[k * NDIM + c]);
        WeT2[c * EDIM + k] = f2bf(We2[k * NDIM + c]);
    }
    W1T[c * NDIM + k] = f2bf(W1[k * NDIM + c]);
    W2T[c * NDIM + k] = f2bf(W2[k * NDIM + c]);
    W3T[c * NDIM + k] = f2bf(W3[k * NDIM + c]);
    W4T[c * NDIM + k] = f2bf(W4[k * NDIM + c]);
}

// ---------------------------------------------------------------------------
// Edge pass: MFMA + software-pipelined segmented accumulate.
// PERM=true : A-fragments loaded sequentially from pre-permuted bf16 eap.
// PERM=false: fallback (random ea via eidp, raw-f32 prefetch+pack).
// ---------------------------------------------------------------------------
template <bool PERM>
__global__ __launch_bounds__(256) void edge_mfma(
    const float* __restrict__ xnode,          // [N,128]
    const float* __restrict__ ea,             // [E,64] edge order (fallback)
    const unsigned short* __restrict__ eap,   // [E,64] bf16 slot order (perm)
    const int*   __restrict__ srcp,           // [E] slot-ordered src
    const int*   __restrict__ eidp,           // [E] slot-ordered edge id
    const int*   __restrict__ dstp,           // [E] slot-ordered dst (sorted)
    const unsigned short* __restrict__ WeT,   // [128][64] bf16
    const float* __restrict__ be,             // [128]
    float*       __restrict__ aggr,           // [N,128] pre-zeroed
    int E)
{
    __shared__ float msg[WPB][16][LPAD];

    const int tid   = threadIdx.x;
    const int lane  = tid & 63;
    const int wv    = tid >> 6;
    const int span0 = (blockIdx.x * WPB + wv) * SPAN;
    if (span0 >= E) return;

    const int m16 = lane & 15;   // A row (slot-within-tile) / C col-within-ntile
    const int kg  = lane >> 4;   // k-group 0..3
    const int k0a = kg * 8;

    // B fragments: full We resident (2 k-tiles x 8 n-tiles = 64 VGPR)
    short8v bfrag[2][8];
#pragma unroll
    for (int kk = 0; kk < 2; ++kk)
#pragma unroll
        for (int nt = 0; nt < 8; ++nt) {
            const int col = nt * 16 + m16;
            bfrag[kk][nt] = *reinterpret_cast<const short8v*>(&WeT[col * EDIM + kk * 32 + k0a]);
        }

    const int c0 = lane, c1 = lane + 64;
    const float be0 = be[c0], be1 = be[c1];
    float* msgw = &msg[wv][0][0];

    float a0 = 0.f, a1 = 0.f;

    if (span0 + SPAN <= E) {
        // ================= fast path (full span) =================
        int   sr_c[16], ds_c[16];
        float xv0_c[16], xv1_c[16];
        short8v af_n[2];    // A-frags for tile t+1 (PERM path)
        short8v af_nn[2];   // A-frags for tile t+2 (PERM path)
        float4 eaf_n[4];    // raw ea tile t+1 (fallback path)
        float4 eaf_nn[4];   // raw ea tile t+2 (fallback path)

        // ---- prologue: tile 0 fully, tile 1 A-stream in flight ----
#pragma unroll
        for (int s = 0; s < 16; ++s) { sr_c[s] = srcp[span0 + s]; ds_c[s] = dstp[span0 + s]; }
#pragma unroll
        for (int s = 0; s < 16; ++s) {
            xv0_c[s] = xnode[(long)sr_c[s] * NDIM + c0];
            xv1_c[s] = xnode[(long)sr_c[s] * NDIM + c1];
        }
        {
            short8v af0, af1;
            if (PERM) {
                const unsigned short* arow = eap + (size_t)(span0 + m16) * EDIM;
                af0 = *reinterpret_cast<const short8v*>(arow + k0a);
                af1 = *reinterpret_cast<const short8v*>(arow + 32 + k0a);
            } else {
                const float* arow = ea + (long)eidp[span0 + m16] * EDIM;
                af0 = cvt_row(arow, k0a);
                af1 = cvt_row(arow, 32 + k0a);
            }
#pragma unroll
            for (int nt = 0; nt < 8; ++nt) {
                float4v acc = (float4v){0.f, 0.f, 0.f, 0.f};
                acc = __builtin_amdgcn_mfma_f32_16x16x32_bf16(af0, bfrag[0][nt], acc, 0, 0, 0);
                acc = __builtin_amdgcn_mfma_f32_16x16x32_bf16(af1, bfrag[1][nt], acc, 0, 0, 0);
#pragma unroll
                for (int r = 0; r < 4; ++r)
                    msgw[(kg * 4 + r) * LPAD + nt * 16 + m16] = acc[r];
            }
        }
        if (PERM) {
            const unsigned short* arow = eap + (size_t)(span0 + 16 + m16) * EDIM;
            af_n[0] = *reinterpret_cast<const short8v*>(arow + k0a);
            af_n[1] = *reinterpret_cast<const short8v*>(arow + 32 + k0a);
        } else {
            const float* arow = ea + (long)eidp[span0 + 16 + m16] * EDIM;
            eaf_n[0] = *reinterpret_cast<const float4*>(arow + k0a);
            eaf_n[1] = *reinterpret_cast<const float4*>(arow + k0a + 4);
            eaf_n[2] = *reinterpret_cast<const float4*>(arow + 32 + k0a);
            eaf_n[3] = *reinterpret_cast<const float4*>(arow + 32 + k0a + 4);
        }

        int dcur = ds_c[0];

#pragma unroll
        for (int t = 0; t < SPAN / 16; ++t) {
            const int base = span0 + t * 16;
            const bool hn  = (t + 1 < SPAN / 16);
            const bool hnn = (t + 2 < SPAN / 16);
            int   sr_n[16], ds_n[16];
            float xv0_n[16], xv1_n[16];

            // ---- phase 1: scalars + x rows for tile t+1 ----
            if (hn) {
#pragma unroll
                for (int s = 0; s < 16; ++s) {
                    sr_n[s] = srcp[base + 16 + s];
                    ds_n[s] = dstp[base + 16 + s];
                }
#pragma unroll
                for (int s = 0; s < 16; ++s) {
                    xv0_n[s] = xnode[(long)sr_n[s] * NDIM + c0];
                    xv1_n[s] = xnode[(long)sr_n[s] * NDIM + c1];
                }
            }

            // ---- phase 2: A-stream loads for tile t+2 ----
            if (hnn) {
                if (PERM) {
                    const unsigned short* arow = eap + (size_t)(base + 32 + m16) * EDIM;
                    af_nn[0] = *reinterpret_cast<const short8v*>(arow + k0a);
                    af_nn[1] = *reinterpret_cast<const short8v*>(arow + 32 + k0a);
                } else {
                    const float* arow = ea + (long)eidp[base + 32 + m16] * EDIM;
                    eaf_nn[0] = *reinterpret_cast<const float4*>(arow + k0a);
                    eaf_nn[1] = *reinterpret_cast<const float4*>(arow + k0a + 4);
                    eaf_nn[2] = *reinterpret_cast<const float4*>(arow + 32 + k0a);
                    eaf_nn[3] = *reinterpret_cast<const float4*>(arow + 32 + k0a + 4);
                }
            }

            // ---- phase 3: flush tile t (registers + LDS only) ----
#pragma unroll
            for (int s = 0; s < 16; ++s) {
                if (ds_c[s] != dcur) {
                    atomicAdd(&aggr[(long)dcur * NDIM + c0], a0);
                    atomicAdd(&aggr[(long)dcur * NDIM + c1], a1);
                    a0 = 0.f; a1 = 0.f; dcur = ds_c[s];
                }
                a0 += fmaxf(xv0_c[s] + msgw[s * LPAD + c0] + be0, 0.f);
                a1 += fmaxf(xv1_c[s] + msgw[s * LPAD + c1] + be1, 0.f);
            }

            // ---- phase 4: MFMA tile t+1 + rotate ----
            if (hn) {
                short8v af0, af1;
                if (PERM) { af0 = af_n[0]; af1 = af_n[1]; }
                else      { af0 = pack_bf(eaf_n[0], eaf_n[1]); af1 = pack_bf(eaf_n[2], eaf_n[3]); }
#pragma unroll
                for (int nt = 0; nt < 8; ++nt) {
                    float4v acc = (float4v){0.f, 0.f, 0.f, 0.f};
                    acc = __builtin_amdgcn_mfma_f32_16x16x32_bf16(af0, bfrag[0][nt], acc, 0, 0, 0);
                    acc = __builtin_amdgcn_mfma_f32_16x16x32_bf16(af1, bfrag[1][nt], acc, 0, 0, 0);
#pragma unroll
                    for (int r = 0; r < 4; ++r)
                        msgw[(kg * 4 + r) * LPAD + nt * 16 + m16] = acc[r];
                }
                if (PERM) {
                    af_n[0] = af_nn[0]; af_n[1] = af_nn[1];
                } else {
#pragma unroll
                    for (int i = 0; i < 4; ++i) eaf_n[i] = eaf_nn[i];
                }
#pragma unroll
                for (int s = 0; s < 16; ++s) {
                    sr_c[s] = sr_n[s]; ds_c[s] = ds_n[s];
                    xv0_c[s] = xv0_n[s]; xv1_c[s] = xv1_n[s];
                }
            }
        }
        atomicAdd(&aggr[(long)dcur * NDIM + c0], a0);
        atomicAdd(&aggr[(long)dcur * NDIM + c1], a1);
    } else {
        // ================= tail slow path =================
        const int spanEnd = E;
        int dcur = dstp[span0];
        for (int t = 0; t < SPAN / 16; ++t) {
            const int base = span0 + t * 16;
            if (base >= spanEnd) break;

            const int slot = (base + m16 < E) ? base + m16 : E - 1;
            short8v afrag[2];
            if (PERM) {
                const unsigned short* arow = eap + (size_t)slot * EDIM;
                afrag[0] = *reinterpret_cast<const short8v*>(arow + k0a);
                afrag[1] = *reinterpret_cast<const short8v*>(arow + 32 + k0a);
            } else {
                const float* arow = ea + (long)eidp[slot] * EDIM;
                afrag[0] = cvt_row(arow, k0a);
                afrag[1] = cvt_row(arow, 32 + k0a);
            }

#pragma unroll
            for (int nt = 0; nt < 8; ++nt) {
                float4v acc = (float4v){0.f, 0.f, 0.f, 0.f};
                acc = __builtin_amdgcn_mfma_f32_16x16x32_bf16(afrag[0], bfrag[0][nt], acc, 0, 0, 0);
                acc = __builtin_amdgcn_mfma_f32_16x16x32_bf16(afrag[1], bfrag[1][nt], acc, 0, 0, 0);
#pragma unroll
                for (int r = 0; r < 4; ++r)
                    msgw[(kg * 4 + r) * LPAD + nt * 16 + m16] = acc[r];
            }

            for (int s = 0; s < 16; ++s) {
                const int gs = base + s;
                if (gs >= spanEnd) break;
                const int d  = dstp[gs];
                const int sr = srcp[gs];
                if (d != dcur) {
                    atomicAdd(&aggr[(long)dcur * NDIM + c0], a0);
                    atomicAdd(&aggr[(long)dcur * NDIM + c1], a1);
                    a0 = 0.f; a1 = 0.f; dcur = d;
                }
                const float xv0 = xnode[(long)sr * NDIM + c0];
                const float xv1 = xnode[(long)sr * NDIM + c1];
                a0 += fmaxf(xv0 + msgw[s * LPAD + c0] + be0, 0.f);
                a1 += fmaxf(xv1 + msgw[s * LPAD + c1] + be1, 0.f);
            }
        }
        atomicAdd(&aggr[(long)dcur * NDIM + c0], a0);
        atomicAdd(&aggr[(long)dcur * NDIM + c1], a1);
    }
}

// ---------------------------------------------------------------------------
// Node MLP via MFMA (kept).
// ---------------------------------------------------------------------------
template <bool FINAL_RELU, bool STATS>
__global__ __launch_bounds__(256) void node_mlp_mfma(
    const float* xin,                    // may alias out (same-row read->write)
    const float* __restrict__ aggr,
    const unsigned short* __restrict__ W1T, const float* __restrict__ b1,
    const unsigned short* __restrict__ W2T, const float* __restrict__ b2,
    float* out,
    float* __restrict__ stats,
    int N)
{
    __shared__ unsigned short in_lds[16][PITCH];
    __shared__ unsigned short t_lds[16][PITCH];

    const int tid  = threadIdx.x;
    const int lane = tid & 63;
    const int wv   = tid >> 6;
    const int wn0  = wv * 32;
    const int m16  = lane & 15;
    const int rg   = lane >> 4;

    short8v b1f[4][2], b2f[4][2];
#pragma unroll
    for (int kt = 0; kt < 4; ++kt)
#pragma unroll
        for (int nt = 0; nt < 2; ++nt) {
            const int col = wn0 + nt * 16 + m16;
            b1f[kt][nt] = *reinterpret_cast<const short8v*>(&W1T[col * NDIM + kt * 32 + rg * 8]);
            b2f[kt][nt] = *reinterpret_cast<const short8v*>(&W2T[col * NDIM + kt * 32 + rg * 8]);
        }
    float bias1[2], bias2[2];
#pragma unroll
    for (int nt = 0; nt < 2; ++nt) {
        bias1[nt] = b1[wn0 + nt * 16 + m16];
        bias2[nt] = b2[wn0 + nt * 16 + m16];
    }

    float ss[2] = {0.f, 0.f}, sq[2] = {0.f, 0.f};

    const int ntile = (N + 15) >> 4;
    for (int tile = blockIdx.x; tile < ntile; tile += gridDim.x) {
        const int nb = tile << 4;

        {
            const int row = tid >> 4;
            const int ch  = tid & 15;
            const int gr  = nb + row;
            short8v pk = (short8v){0, 0, 0, 0, 0, 0, 0, 0};
            if (gr < N) {
                const float4* xp = reinterpret_cast<const float4*>(xin  + (size_t)gr * NDIM + ch * 8);
                const float4* ap = reinterpret_cast<const float4*>(aggr + (size_t)gr * NDIM + ch * 8);
                const float4 x0 = xp[0], x1 = xp[1];
                const float4 g0 = ap[0], g1 = ap[1];
                pk[0] = (short)f2bf(x0.x + g0.x); pk[1] = (short)f2bf(x0.y + g0.y);
                pk[2] = (short)f2bf(x0.z + g0.z); pk[3] = (short)f2bf(x0.w + g0.w);
                pk[4] = (short)f2bf(x1.x + g1.x); pk[5] = (short)f2bf(x1.y + g1.y);
                pk[6] = (short)f2bf(x1.z + g1.z); pk[7] = (short)f2bf(x1.w + g1.w);
            }
            *reinterpret_cast<short8v*>(&in_lds[row][ch * 8]) = pk;
        }
        __syncthreads();

        short8v af[4];
#pragma unroll
        for (int kt = 0; kt < 4; ++kt)
            af[kt] = *reinterpret_cast<const short8v*>(&in_lds[m16][kt * 32 + rg * 8]);
        float4v acc[2];
#pragma unroll
        for (int nt = 0; nt < 2; ++nt) {
            acc[nt] = (float4v){0.f, 0.f, 0.f, 0.f};
#pragma unroll
            for (int kt = 0; kt < 4; ++kt)
                acc[nt] = __builtin_amdgcn_mfma_f32_16x16x32_bf16(af[kt], b1f[kt][nt], acc[nt], 0, 0, 0);
        }
#pragma unroll
        for (int nt = 0; nt < 2; ++nt)
#pragma unroll
            for (int r = 0; r < 4; ++r) {
                const float v = fmaxf(acc[nt][r] + bias1[nt], 0.f);
                t_lds[rg * 4 + r][wn0 + nt * 16 + m16] = f2bf(v);
            }
        __syncthreads();

#pragma unroll
        for (int kt = 0; kt < 4; ++kt)
            af[kt] = *reinterpret_cast<const short8v*>(&t_lds[m16][kt * 32 + rg * 8]);
        float4v acc2[2];
#pragma unroll
        for (int nt = 0; nt < 2; ++nt) {
            acc2[nt] = (float4v){0.f, 0.f, 0.f, 0.f};
#pragma unroll
            for (int kt = 0; kt < 4; ++kt)
                acc2[nt] = __builtin_amdgcn_mfma_f32_16x16x32_bf16(af[kt], b2f[kt][nt], acc2[nt], 0, 0, 0);
        }

#pragma unroll
        for (int nt = 0; nt < 2; ++nt)
#pragma unroll
            for (int r = 0; r < 4; ++r) {
                const int node = nb + rg * 4 + r;
                if (node < N) {
                    float o = acc2[nt][r] + bias2[nt];
                    if (FINAL_RELU) o = fmaxf(o, 0.f);
                    out[(size_t)node * NDIM + wn0 + nt * 16 + m16] = o;
                    if (STATS) { ss[nt] += o; sq[nt] += o * o; }
                }
            }
    }

    if (STATS) {
#pragma unroll
        for (int nt = 0; nt < 2; ++nt) {
            float s = ss[nt], q = sq[nt];
            s += __shfl_xor(s, 16); q += __shfl_xor(q, 16);
            s += __shfl_xor(s, 32); q += __shfl_xor(q, 32);
            if (rg == 0) {
                atomicAdd(&stats[wn0 + nt * 16 + m16], s);
                atomicAdd(&stats[NDIM + wn0 + nt * 16 + m16], q);
            }
        }
    }
}

// ---------------------------------------------------------------------------
// BatchNorm apply (in place).
// ---------------------------------------------------------------------------
__global__ __launch_bounds__(256) void bn_apply(
    float* out,
    const float* __restrict__ stats,
    const float* __restrict__ gamma,
    const float* __restrict__ beta,
    int N)
{
    __shared__ float sc_s[NDIM];
    __shared__ float sh_s[NDIM];
    const float invN = 1.f / (float)N;
    if (threadIdx.x < NDIM) {
        const int f = threadIdx.x;
        const float mean = stats[f] * invN;
        const float var  = stats[NDIM + f] * invN - mean * mean;
        const float sc   = gamma[f] * rsqrtf(var + BN_EPS);
        sc_s[f] = sc;
        sh_s[f] = beta[f] - mean * sc;
    }
    __syncthreads();

    const int total4 = N * (NDIM / 4);
    float4* o4 = reinterpret_cast<float4*>(out);
    for (int idx = blockIdx.x * blockDim.x + threadIdx.x; idx < total4;
         idx += gridDim.x * blockDim.x) {
        const int fb = (idx & 31) * 4;
        float4 p = o4[idx];
        p.x = p.x * sc_s[fb + 0] + sh_s[fb + 0];
        p.y = p.y * sc_s[fb + 1] + sh_s[fb + 1];
        p.z = p.z * sc_s[fb + 2] + sh_s[fb + 2];
        p.w = p.w * sc_s[fb + 3] + sh_s[fb + 3];
        o4[idx] = p;
    }
}

// ---------------------------------------------------------------------------
extern "C" void kernel_launch(void* const* d_in, const int* in_sizes, int n_in,
                              void* d_out, int out_size, void* d_ws, size_t ws_size,
                              hipStream_t stream)
{
    const float* x    = (const float*)d_in[0];
    const int*   ei   = (const int*)  d_in[1];
    const float* ea   = (const float*)d_in[2];
    const float* We1  = (const float*)d_in[3];
    const float* be1  = (const float*)d_in[4];
    const float* W1   = (const float*)d_in[5];
    const float* b1   = (const float*)d_in[6];
    const float* W2   = (const float*)d_in[7];
    const float* b2   = (const float*)d_in[8];
    const float* We2  = (const float*)d_in[9];
    const float* be2  = (const float*)d_in[10];
    const float* W3   = (const float*)d_in[11];
    const float* b3   = (const float*)d_in[12];
    const float* W4   = (const float*)d_in[13];
    const float* b4   = (const float*)d_in[14];
    const float* gamma = (const float*)d_in[15];
    const float* beta  = (const float*)d_in[16];

    const int N = in_sizes[0] / NDIM;
    const int E = in_sizes[1] / 2;

    // workspace layout (aggr first; all 16B-aligned)
    float*          aggr   = (float*)d_ws;                            // [N*128]
    unsigned short* WeT1   = (unsigned short*)(aggr + (size_t)N * NDIM);
    unsigned short* WeT2   = WeT1 + NDIM * EDIM;
    unsigned short* W1T    = WeT2 + NDIM * EDIM;                      // [128*128]
    unsigned short* W2T    = W1T + NDIM * NDIM;
    unsigned short* W3T    = W2T + NDIM * NDIM;
    unsigned short* W4T    = W3T + NDIM * NDIM;
    int*            rowptr = (int*)(W4T + NDIM * NDIM);               // [N+1]
    int*            cursor = rowptr + (N + 1);                        // [N]
    int*            srcp   = cursor + N;                              // [E]
    int*            dstp   = srcp + E;                                // [E]
    int*            eidp   = dstp + E;                                // [E]
    float*          stats  = (float*)(eidp + E);                      // [256]
    unsigned short* eap    = (unsigned short*)(stats + 2 * NDIM);     // [E*64] bf16

    const size_t need_perm = (size_t)((char*)eap - (char*)d_ws) + (size_t)E * EDIM * 2 + 64;
    const bool   perm      = ws_size >= need_perm;

    hipMemsetAsync(cursor, 0, (size_t)N * sizeof(int), stream);
    hipMemsetAsync(stats, 0, 2 * NDIM * sizeof(float), stream);

    // ---- CSR build + weight prep ----
    hist_k<<<(E + 255) / 256, 256, 0, stream>>>(ei, cursor, E);
    scan_build<<<1, 1024, 0, stream>>>(cursor, rowptr, N);
    scatter_k<<<(E + 255) / 256, 256, 0, stream>>>(ei, cursor, srcp, dstp, eidp, E);
    prep_all<<<NDIM, NDIM, 0, stream>>>(We1, We2, W1, W2, W3, W4,
                                        WeT1, WeT2, W1T, W2T, W3T, W4T);
    if (perm)
        permute_ea<<<2048, 256, 0, stream>>>(ea, eidp, eap, E);

    const int egrid = (E + WPB * SPAN - 1) / (WPB * SPAN);
    const int mgrid = 625;
    float* h = (float*)d_out;

    // ---- conv1 ----
    hipMemsetAsync(aggr, 0, (size_t)N * NDIM * sizeof(float), stream);
    if (perm)
        edge_mfma<true><<<egrid, 256, 0, stream>>>(x, ea, eap, srcp, eidp, dstp, WeT1, be1, aggr, E);
    else
        edge_mfma<false><<<egrid, 256, 0, stream>>>(x, ea, eap, srcp, eidp, dstp, WeT1, be1, aggr, E);
    node_mlp_mfma<true, false><<<mgrid, 256, 0, stream>>>(x, aggr, W1T, b1, W2T, b2,
                                                          h, nullptr, N);
    // ---- conv2 ----
    hipMemsetAsync(aggr, 0, (size_t)N * NDIM * sizeof(float), stream);
    if (perm)
        edge_mfma<true><<<egrid, 256, 0, stream>>>(h, ea, eap, srcp, eidp, dstp, WeT2, be2, aggr, E);
    else
        edge_mfma<false><<<egrid, 256, 0, stream>>>(h, ea, eap, srcp, eidp, dstp, WeT2, be2, aggr, E);
    node_mlp_mfma<false, true><<<mgrid, 256, 0, stream>>>(h, aggr, W3T, b3, W4T, b4,
                                                          h, stats, N);
    // ---- batch norm ----
    bn_apply<<<1024, 256, 0, stream>>>(h, stats, gamma, beta, N);
}